// Round 5
// baseline (697.555 us; speedup 1.0000x reference)
//
#include <hip/hip_runtime.h>
#include <hip/hip_cooperative_groups.h>
#include <math.h>

namespace cg = cooperative_groups;

#define N_NODES 50000
#define N_EDGES 800000
#define F_IN    128
#define HID     256
#define BN_EPS  1e-5f
#define SCAN_BLOCKS ((N_NODES + 255) / 256)   // 196
#define RB256       ((N_NODES + 255) / 256)   // 196 gemm row-blocks

typedef unsigned int uint;
typedef __attribute__((ext_vector_type(8))) short bf16x8;  // 8 bf16 = 4 VGPRs
typedef __attribute__((ext_vector_type(4))) float f32x4;

__device__ __forceinline__ float bf2f(unsigned short u) {
    return __uint_as_float((uint)u << 16);
}
__device__ __forceinline__ unsigned short f2bf(float f) {   // RTNE
    uint u = __float_as_uint(f);
    return (unsigned short)((u + 0x7FFFu + ((u >> 16) & 1u)) >> 16);
}

// async global->LDS, 16B per lane; LDS dest = wave-uniform base + lane*16
__device__ __forceinline__ void gload16(const unsigned short* g, unsigned short* l) {
    __builtin_amdgcn_global_load_lds(
        (const __attribute__((address_space(1))) void*)g,
        (__attribute__((address_space(3))) void*)l, 16, 0, 0);
}

// accumulate 8 bf16 of a uint4 into acc[8]
__device__ __forceinline__ void acc_u4(float* a, uint4 v) {
    a[0] += bf2f((unsigned short)(v.x & 0xFFFF)); a[1] += bf2f((unsigned short)(v.x >> 16));
    a[2] += bf2f((unsigned short)(v.y & 0xFFFF)); a[3] += bf2f((unsigned short)(v.y >> 16));
    a[4] += bf2f((unsigned short)(v.z & 0xFFFF)); a[5] += bf2f((unsigned short)(v.z >> 16));
    a[6] += bf2f((unsigned short)(v.w & 0xFFFF)); a[7] += bf2f((unsigned short)(v.w >> 16));
}
__device__ __forceinline__ void acc_u4m(float* a, uint4 v, float m) {
    a[0] += m * bf2f((unsigned short)(v.x & 0xFFFF)); a[1] += m * bf2f((unsigned short)(v.x >> 16));
    a[2] += m * bf2f((unsigned short)(v.y & 0xFFFF)); a[3] += m * bf2f((unsigned short)(v.y >> 16));
    a[4] += m * bf2f((unsigned short)(v.z & 0xFFFF)); a[5] += m * bf2f((unsigned short)(v.z >> 16));
    a[6] += m * bf2f((unsigned short)(v.w & 0xFFFF)); a[7] += m * bf2f((unsigned short)(v.w >> 16));
}

// ---------------------------------------------------------------- CSR build
__global__ void hist_kernel(const int* __restrict__ dst, int* __restrict__ deg) {
    int e = blockIdx.x * blockDim.x + threadIdx.x;
    if (e < N_EDGES) atomicAdd(&deg[dst[e]], 1);
}

__global__ __launch_bounds__(256) void scan1_kernel(const int* __restrict__ deg,
                                                    int* __restrict__ row_ptr,
                                                    int* __restrict__ partials) {
    __shared__ int sm[256];
    int i = blockIdx.x * 256 + threadIdx.x;
    int v = (i < N_NODES) ? deg[i] : 0;
    sm[threadIdx.x] = v;
    __syncthreads();
    for (int off = 1; off < 256; off <<= 1) {
        int t = (threadIdx.x >= off) ? sm[threadIdx.x - off] : 0;
        __syncthreads();
        sm[threadIdx.x] += t;
        __syncthreads();
    }
    if (i < N_NODES) row_ptr[i] = sm[threadIdx.x] - v;   // tile-local exclusive
    if (threadIdx.x == 255) partials[blockIdx.x] = sm[255];
}

__global__ __launch_bounds__(256) void scan2_kernel(int* __restrict__ partials) {
    __shared__ int sm[256];
    int t = threadIdx.x;
    int v = (t < SCAN_BLOCKS) ? partials[t] : 0;
    sm[t] = v;
    __syncthreads();
    for (int off = 1; off < 256; off <<= 1) {
        int p = (t >= off) ? sm[t - off] : 0;
        __syncthreads();
        sm[t] += p;
        __syncthreads();
    }
    if (t < SCAN_BLOCKS) partials[t] = sm[t] - v;        // exclusive base
}

__global__ __launch_bounds__(256) void scan3_kernel(int* __restrict__ row_ptr,
                                                    int* __restrict__ cursor,
                                                    const int* __restrict__ partials) {
    int i = blockIdx.x * 256 + threadIdx.x;
    if (i < N_NODES) {
        int v = row_ptr[i] + partials[blockIdx.x];
        row_ptr[i] = v;
        cursor[i]  = v;
    }
    if (i == 0) row_ptr[N_NODES] = N_EDGES;
}

__global__ void fill_kernel(const int* __restrict__ src, const int* __restrict__ dst,
                            int* __restrict__ cursor, int* __restrict__ csr_src) {
    int e = blockIdx.x * blockDim.x + threadIdx.x;
    if (e >= N_EDGES) return;
    int pos = atomicAdd(&cursor[dst[e]], 1);
    __builtin_nontemporal_store(src[e], &csr_src[pos]);   // nt: avoid cross-XCD line bounce
}

// ---------------------------------------------------------------- cast x -> bf16
__global__ void cast_bf16_kernel(const float* __restrict__ x, unsigned short* __restrict__ xb,
                                 int total4) {
    int i = blockIdx.x * blockDim.x + threadIdx.x;
    if (i >= total4) return;
    float4 v = *(const float4*)&x[(long)i * 4];
    unsigned short o[4] = {f2bf(v.x), f2bf(v.y), f2bf(v.z), f2bf(v.w)};
    *(uint2*)&xb[(long)i * 4] = *(const uint2*)o;
}

// ---------------------------------------------------------------- weight transpose
// WT[n][k] bf16, k < K1 from Wn[k][n], else Wr[k-K1][n].
__global__ __launch_bounds__(256) void wt_kernel(const float* __restrict__ Wn,
                                                 const float* __restrict__ Wr,
                                                 int K1, int KT, unsigned short* __restrict__ WT) {
    int n  = threadIdx.x;     // 0..255
    int k0 = blockIdx.x * 16;
    unsigned short o[16];
#pragma unroll
    for (int j = 0; j < 16; ++j) {
        int k = k0 + j;
        float v = (k < K1) ? Wn[k * HID + n] : Wr[(k - K1) * HID + n];
        o[j] = f2bf(v);
    }
    *(uint4*)&WT[(long)n * KT + k0]     = *(const uint4*)&o[0];
    *(uint4*)&WT[(long)n * KT + k0 + 8] = *(const uint4*)&o[8];
}

// ---------------------------------------------------------------- gather-mean (bf16)
// uint4 (16B/lane) loads; 16-edge unrolled groups keep 8 (D=256) / 4 (D=128)
// independent 16B loads in flight per thread (latency-bound kernel, VALUBusy 35%).
template<int D>
__global__ __launch_bounds__(256) void gather_mean_kernel(
    const unsigned short* __restrict__ x, const int* __restrict__ row_ptr,
    const int* __restrict__ csr_src, unsigned short* __restrict__ agg) {
    int node = blockIdx.x * 4 + (threadIdx.x >> 6);
    int lane = threadIdx.x & 63;
    if (node >= N_NODES) return;
    int beg = row_ptr[node], end = row_ptr[node + 1];
    float acc[8];
#pragma unroll
    for (int j = 0; j < 8; j++) acc[j] = 0.f;
    int e = beg;

    if constexpr (D == 256) {
        const int half = lane >> 5;          // which edge of the pair
        const long lo  = (long)(lane & 31) * 8;
        for (; e + 16 <= end; e += 16) {
            int s0 = csr_src[e + half],      s1 = csr_src[e + 2 + half];
            int s2 = csr_src[e + 4 + half],  s3 = csr_src[e + 6 + half];
            int s4 = csr_src[e + 8 + half],  s5 = csr_src[e + 10 + half];
            int s6 = csr_src[e + 12 + half], s7 = csr_src[e + 14 + half];
            uint4 v0 = *(const uint4*)&x[(long)s0 * 256 + lo];
            uint4 v1 = *(const uint4*)&x[(long)s1 * 256 + lo];
            uint4 v2 = *(const uint4*)&x[(long)s2 * 256 + lo];
            uint4 v3 = *(const uint4*)&x[(long)s3 * 256 + lo];
            uint4 v4 = *(const uint4*)&x[(long)s4 * 256 + lo];
            uint4 v5 = *(const uint4*)&x[(long)s5 * 256 + lo];
            uint4 v6 = *(const uint4*)&x[(long)s6 * 256 + lo];
            uint4 v7 = *(const uint4*)&x[(long)s7 * 256 + lo];
            acc_u4(acc, v0); acc_u4(acc, v1); acc_u4(acc, v2); acc_u4(acc, v3);
            acc_u4(acc, v4); acc_u4(acc, v5); acc_u4(acc, v6); acc_u4(acc, v7);
        }
        for (; e + 8 <= end; e += 8) {
            int s0 = csr_src[e + half],     s1 = csr_src[e + 2 + half];
            int s2 = csr_src[e + 4 + half], s3 = csr_src[e + 6 + half];
            uint4 v0 = *(const uint4*)&x[(long)s0 * 256 + lo];
            uint4 v1 = *(const uint4*)&x[(long)s1 * 256 + lo];
            uint4 v2 = *(const uint4*)&x[(long)s2 * 256 + lo];
            uint4 v3 = *(const uint4*)&x[(long)s3 * 256 + lo];
            acc_u4(acc, v0); acc_u4(acc, v1); acc_u4(acc, v2); acc_u4(acc, v3);
        }
        for (; e + 2 <= end; e += 2) {
            int s0 = csr_src[e + half];
            uint4 v0 = *(const uint4*)&x[(long)s0 * 256 + lo];
            acc_u4(acc, v0);
        }
        if (e < end) {                        // single tail edge: mask half 1
            int s0 = csr_src[e];
            uint4 v0 = *(const uint4*)&x[(long)s0 * 256 + lo];
            acc_u4m(acc, v0, (half == 0) ? 1.f : 0.f);
        }
#pragma unroll
        for (int j = 0; j < 8; j++) acc[j] += __shfl_xor(acc[j], 32);
        float inv = 1.0f / fmaxf((float)(end - beg), 1.0f);
        if (half == 0) {
            unsigned short ov[8];
#pragma unroll
            for (int j = 0; j < 8; j++) ov[j] = f2bf(acc[j] * inv);
            *(uint4*)&agg[(long)node * 256 + lo] = *(const uint4*)ov;
        }
    } else {   // D == 128
        const int grp = lane >> 4;           // which edge of the quad
        const long lo = (long)(lane & 15) * 8;
        for (; e + 16 <= end; e += 16) {
            int sA = csr_src[e + grp],     sB = csr_src[e + 4 + grp];
            int sC = csr_src[e + 8 + grp], sD = csr_src[e + 12 + grp];
            uint4 vA = *(const uint4*)&x[(long)sA * 128 + lo];
            uint4 vB = *(const uint4*)&x[(long)sB * 128 + lo];
            uint4 vC = *(const uint4*)&x[(long)sC * 128 + lo];
            uint4 vD = *(const uint4*)&x[(long)sD * 128 + lo];
            acc_u4(acc, vA); acc_u4(acc, vB); acc_u4(acc, vC); acc_u4(acc, vD);
        }
        for (; e + 8 <= end; e += 8) {
            int sA = csr_src[e + grp], sB = csr_src[e + 4 + grp];
            uint4 vA = *(const uint4*)&x[(long)sA * 128 + lo];
            uint4 vB = *(const uint4*)&x[(long)sB * 128 + lo];
            acc_u4(acc, vA); acc_u4(acc, vB);
        }
        for (; e + 4 <= end; e += 4) {
            int sA = csr_src[e + grp];
            uint4 vA = *(const uint4*)&x[(long)sA * 128 + lo];
            acc_u4(acc, vA);
        }
        for (; e < end; e++) {                // up to 3 tail edges: mask grp>0
            int s0 = csr_src[e];
            uint4 v0 = *(const uint4*)&x[(long)s0 * 128 + lo];
            acc_u4m(acc, v0, (grp == 0) ? 1.f : 0.f);
        }
#pragma unroll
        for (int j = 0; j < 8; j++) {
            acc[j] += __shfl_xor(acc[j], 32);
            acc[j] += __shfl_xor(acc[j], 16);
        }
        float inv = 1.0f / fmaxf((float)(end - beg), 1.0f);
        if (lane < 16) {
            unsigned short ov[8];
#pragma unroll
            for (int j = 0; j < 8; j++) ov[j] = f2bf(acc[j] * inv);
            *(uint4*)&agg[(long)node * 128 + lo] = *(const uint4*)ov;
        }
    }
}

// ---------------------------------------------------------------- fused MFMA GEMM + BN + ELU
// Cooperative launch, 196 blocks (1/CU at 128KB LDS -> co-residency guaranteed).
// Phase 1: 256x256-tile GEMM (counted-vmcnt double-buffer), bias into acc,
//          per-block BN column partials -> sred (plain stores).
// grid.sync()
// Phase 2: every block reduces the 392x512 partials (L2-resident, ~5us aggregate),
//          builds per-channel scale/shift in LDS, applies BN+ELU to its acc
//          IN REGISTERS and writes activations directly (no H round-trip,
//          no bn_reduce/bn_elu dispatches; 51.2 MB/layer traffic removed).
template<int K1, int K2, bool OUT32>
__global__ __launch_bounds__(512) void mfma_gemm_fused(
    const unsigned short* __restrict__ A1, const unsigned short* __restrict__ A2,
    const unsigned short* __restrict__ WT, const float* __restrict__ bias,
    const float* __restrict__ gam, const float* __restrict__ bet,
    void* __restrict__ actout, float* __restrict__ sred) {
    constexpr int KT = K1 + K2;
    constexpr int NITER = KT / 64;
    constexpr int NROWS = 2 * RB256;             // 392 partial rows
    __shared__ unsigned short As[2][256 * 64];   // 2 x 32 KB, chunk-swizzled
    __shared__ unsigned short Bs[2][256 * 64];   // 2 x 32 KB, chunk-swizzled
    __shared__ float ssm[512];                   // S|Q sums -> scale|shift

    const int tid  = threadIdx.x;
    const int wave = tid >> 6;                // 0..7
    const int lane = tid & 63;
    const int m16  = lane & 15;
    const int quad = lane >> 4;
    const int WR   = wave >> 2;               // 0..1 (row 128-half)
    const int WC   = wave & 3;                // 0..3 (col 64-quarter)
    const int r0   = blockIdx.x * 256;
    const int rl = lane >> 3;                 // staging: row within 8-group
    const int cl = lane & 7;                  // staging: logical chunk
    const int csw = cl ^ rl;                  // swizzled chunk fetched by this lane

    f32x4 acc[8][4];
#pragma unroll
    for (int mt = 0; mt < 8; mt++)
#pragma unroll
        for (int nt = 0; nt < 4; nt++) acc[mt][nt] = (f32x4){0.f, 0.f, 0.f, 0.f};

    // issue one 64-k tile's 8 global_load_lds per wave (4 A + 4 B) into buf t&1
    auto issue = [&](int t) {
        const int buf = t & 1;
        const int k0  = t * 64;
        const unsigned short* Ab;
        int pitch, kk;
        if (k0 < K1) { Ab = A1; pitch = K1; kk = k0; }
        else         { Ab = A2; pitch = K2; kk = k0 - K1; }
#pragma unroll
        for (int j = 0; j < 4; ++j) {
            int lr = wave * 32 + j * 8 + rl;
            long gr = min(r0 + lr, N_NODES - 1);
            gload16(&Ab[gr * pitch + kk + csw * 8], &As[buf][(wave * 32 + j * 8) * 64]);
        }
#pragma unroll
        for (int j = 0; j < 4; ++j) {
            long gn = wave * 32 + j * 8 + rl;   // B rows = output cols 0..255
            gload16(&WT[gn * KT + k0 + csw * 8], &Bs[buf][(wave * 32 + j * 8) * 64]);
        }
    };

    issue(0);

#pragma unroll
    for (int it = 0; it < NITER; ++it) {
        const int cur = it & 1;
        if (it + 1 < NITER) {
            issue(it + 1);                                   // 8 new loads in flight
            asm volatile("s_waitcnt vmcnt(8)" ::: "memory"); // tile it retired; it+1 stays out
        } else {
            asm volatile("s_waitcnt vmcnt(0)" ::: "memory");
        }
        __builtin_amdgcn_s_barrier();                        // tile it visible block-wide
#pragma unroll
        for (int ks = 0; ks < 2; ++ks) {
            bf16x8 afrag[8], bfrag[4];
#pragma unroll
            for (int mt = 0; mt < 8; mt++) {
                int ar = WR * 128 + mt * 16 + m16;
                afrag[mt] = *(const bf16x8*)&As[cur][ar * 64 + (((ks * 4 + quad) ^ (m16 & 7)) * 8)];
            }
#pragma unroll
            for (int nt = 0; nt < 4; nt++) {
                int br = WC * 64 + nt * 16 + m16;
                bfrag[nt] = *(const bf16x8*)&Bs[cur][br * 64 + (((ks * 4 + quad) ^ (m16 & 7)) * 8)];
            }
#pragma unroll
            for (int mt = 0; mt < 8; mt++)
#pragma unroll
                for (int nt = 0; nt < 4; nt++)
                    acc[mt][nt] = __builtin_amdgcn_mfma_f32_16x16x32_bf16(
                        afrag[mt], bfrag[nt], acc[mt][nt], 0, 0, 0);
        }
        __builtin_amdgcn_s_barrier();                        // buffer cur free next iter
    }

    // phase-1 epilogue: bias into acc, BN column partials (plain stores)
#pragma unroll
    for (int nt = 0; nt < 4; nt++) {
        int lcol = WC * 64 + nt * 16 + m16;
        float bv = bias[lcol];
        float s = 0.f, q = 0.f;
#pragma unroll
        for (int mt = 0; mt < 8; mt++) {
#pragma unroll
            for (int reg = 0; reg < 4; reg++) {
                int row = r0 + WR * 128 + mt * 16 + quad * 4 + reg;
                float v = acc[mt][nt][reg] + bv;
                acc[mt][nt][reg] = v;
                if (row < N_NODES) { s += v; q += v * v; }
            }
        }
        s += __shfl_xor(s, 16); s += __shfl_xor(s, 32);
        q += __shfl_xor(q, 16); q += __shfl_xor(q, 32);
        if (quad == 0) {
            float* base = &sred[(long)(blockIdx.x * 2 + WR) * 512];
            base[lcol]       = s;
            base[256 + lcol] = q;
        }
    }

    cg::this_grid().sync();

    // phase 2: full reduce (thread t sums column t of the 392x512 partials)
    {
        float S0 = 0.f, S1 = 0.f, S2 = 0.f, S3 = 0.f;
#pragma unroll 1
        for (int rb = 0; rb < NROWS; rb += 4) {
            S0 += sred[(long)(rb + 0) * 512 + tid];
            S1 += sred[(long)(rb + 1) * 512 + tid];
            S2 += sred[(long)(rb + 2) * 512 + tid];
            S3 += sred[(long)(rb + 3) * 512 + tid];
        }
        ssm[tid] = (S0 + S1) + (S2 + S3);
    }
    __syncthreads();
    if (tid < 256) {
        float mu  = ssm[tid] * (1.0f / N_NODES);
        float var = ssm[256 + tid] * (1.0f / N_NODES) - mu * mu;
        var = fmaxf(var, 0.f);
        float sc = rsqrtf(var + BN_EPS) * gam[tid];
        ssm[tid]       = sc;
        ssm[256 + tid] = bet[tid] - mu * sc;
    }
    __syncthreads();

    // apply BN+ELU in-register, store activations
#pragma unroll
    for (int nt = 0; nt < 4; nt++) {
        int lcol = WC * 64 + nt * 16 + m16;
        float sc = ssm[lcol];
        float sh = ssm[256 + lcol];
#pragma unroll
        for (int mt = 0; mt < 8; mt++) {
#pragma unroll
            for (int reg = 0; reg < 4; reg++) {
                int row = r0 + WR * 128 + mt * 16 + quad * 4 + reg;
                if (row < N_NODES) {
                    float t = fmaf(acc[mt][nt][reg], sc, sh);
                    float o = t > 0.f ? t : expm1f(t);
                    if (OUT32) ((float*)actout)[(long)row * HID + lcol] = o;
                    else       ((unsigned short*)actout)[(long)row * HID + lcol] = f2bf(o);
                }
            }
        }
    }
}

// ---------------------------------------------------------------- launch
extern "C" void kernel_launch(void* const* d_in, const int* in_sizes, int n_in,
                              void* d_out, int out_size, void* d_ws, size_t ws_size,
                              hipStream_t stream) {
    const float* x   = (const float*)d_in[0];
    const int*   ei  = (const int*)d_in[1];
    const int*   src = ei;
    const int*   dst = ei + N_EDGES;
    const float* Wn[3] = {(const float*)d_in[2],  (const float*)d_in[7],  (const float*)d_in[12]};
    const float* bn[3] = {(const float*)d_in[3],  (const float*)d_in[8],  (const float*)d_in[13]};
    const float* Wr[3] = {(const float*)d_in[4],  (const float*)d_in[9],  (const float*)d_in[14]};
    const float* g [3] = {(const float*)d_in[5],  (const float*)d_in[10], (const float*)d_in[15]};
    const float* b [3] = {(const float*)d_in[6],  (const float*)d_in[11], (const float*)d_in[16]};
    float* out = (float*)d_out;

    const size_t BF = (size_t)N_NODES * HID * 2;   // 25.6 MB (bf16 N x 256)
    char* ws = (char*)d_ws;
    unsigned short* B0  = (unsigned short*)(ws);                  // agg bf16
    unsigned short* B1  = (unsigned short*)(ws + BF);             // (spare)
    unsigned short* B2  = (unsigned short*)(ws + 2 * BF);         // activations bf16
    unsigned short* XB  = (unsigned short*)(ws + 3 * BF);         // x bf16 [N,128] 12.8 MB
    char* ws2 = ws + 3 * BF + (size_t)N_NODES * F_IN * 2;
    unsigned short* WT0 = (unsigned short*)(ws2);                 // [256][256]
    unsigned short* WT1 = (unsigned short*)(ws2 + 256 * 256 * 2); // [256][512]
    unsigned short* WT2 = (unsigned short*)(ws2 + 256 * 256 * 2 + 256 * 512 * 2);
    char* ws3 = ws2 + 256 * 256 * 2 + 2 * (256 * 512 * 2);
    int*   row_ptr = (int*)ws3;
    int*   cursor  = row_ptr + (N_NODES + 1);
    int*   deg_i   = cursor + N_NODES;
    int*   partial = deg_i + N_NODES;
    int*   csr_src = partial + SCAN_BLOCKS;
    float* sred    = (float*)(csr_src + N_EDGES);        // [2*RB256][512] partials

    const int eb = (N_EDGES + 255) / 256;
    const int gather_blocks = (N_NODES + 3) / 4;

    // ---------------- one-time per call: CSR + bf16 weights/x
    hipMemsetAsync(deg_i, 0, N_NODES * sizeof(int), stream);
    hist_kernel<<<eb, 256, 0, stream>>>(dst, deg_i);
    scan1_kernel<<<SCAN_BLOCKS, 256, 0, stream>>>(deg_i, row_ptr, partial);
    scan2_kernel<<<1, 256, 0, stream>>>(partial);
    scan3_kernel<<<SCAN_BLOCKS, 256, 0, stream>>>(row_ptr, cursor, partial);
    fill_kernel<<<eb, 256, 0, stream>>>(src, dst, cursor, csr_src);
    cast_bf16_kernel<<<(N_NODES * F_IN / 4 + 255) / 256, 256, 0, stream>>>(x, XB, N_NODES * F_IN / 4);
    wt_kernel<<<(2 * F_IN) / 16, 256, 0, stream>>>(Wn[0], Wr[0], F_IN, 2 * F_IN, WT0);
    wt_kernel<<<(2 * HID) / 16, 256, 0, stream>>>(Wn[1], Wr[1], HID, 2 * HID, WT1);
    wt_kernel<<<(2 * HID) / 16, 256, 0, stream>>>(Wn[2], Wr[2], HID, 2 * HID, WT2);

    // ---------------- layer 0: XB[N,128] -> act B2
    gather_mean_kernel<F_IN><<<gather_blocks, 256, 0, stream>>>(XB, row_ptr, csr_src, B0);
    {
        const unsigned short* a1 = B0; const unsigned short* a2 = XB; const unsigned short* wt = WT0;
        const float* bi = bn[0]; const float* gg = g[0]; const float* bb = b[0];
        void* ao = (void*)B2; float* sr = sred;
        void* args[8] = {&a1, &a2, &wt, &bi, &gg, &bb, &ao, &sr};
        hipLaunchCooperativeKernel(reinterpret_cast<const void*>(&mfma_gemm_fused<F_IN, F_IN, false>),
                                   dim3(RB256), dim3(512), args, 0, stream);
    }

    // ---------------- layer 1: B2 -> act B2 (in-place safe: grid sync separates RAW)
    gather_mean_kernel<HID><<<gather_blocks, 256, 0, stream>>>(B2, row_ptr, csr_src, B0);
    {
        const unsigned short* a1 = B0; const unsigned short* a2 = B2; const unsigned short* wt = WT1;
        const float* bi = bn[1]; const float* gg = g[1]; const float* bb = b[1];
        void* ao = (void*)B2; float* sr = sred;
        void* args[8] = {&a1, &a2, &wt, &bi, &gg, &bb, &ao, &sr};
        hipLaunchCooperativeKernel(reinterpret_cast<const void*>(&mfma_gemm_fused<HID, HID, false>),
                                   dim3(RB256), dim3(512), args, 0, stream);
    }

    // ---------------- layer 2: B2 -> out (fp32)
    gather_mean_kernel<HID><<<gather_blocks, 256, 0, stream>>>(B2, row_ptr, csr_src, B0);
    {
        const unsigned short* a1 = B0; const unsigned short* a2 = B2; const unsigned short* wt = WT2;
        const float* bi = bn[2]; const float* gg = g[2]; const float* bb = b[2];
        void* ao = (void*)out; float* sr = sred;
        void* args[8] = {&a1, &a2, &wt, &bi, &gg, &bb, &ao, &sr};
        hipLaunchCooperativeKernel(reinterpret_cast<const void*>(&mfma_gemm_fused<HID, HID, true>),
                                   dim3(RB256), dim3(512), args, 0, stream);
    }
}

// Round 6
// 662.635 us; speedup vs baseline: 1.0527x; 1.0527x over previous
//
#include <hip/hip_runtime.h>
#include <math.h>

#define N_NODES 50000
#define N_EDGES 800000
#define F_IN    128
#define HID     256
#define BN_EPS  1e-5f
#define SCAN_BLOCKS ((N_NODES + 255) / 256)   // 196
#define RB256       ((N_NODES + 255) / 256)   // 196 gemm row-blocks
#define CAST_BLOCKS (N_NODES * F_IN / 4 / 256) // 6250 exact
#define WT_BLOCKS   (16 + 32 + 32)             // 80

typedef unsigned int uint;
typedef __attribute__((ext_vector_type(8))) short bf16x8;  // 8 bf16 = 4 VGPRs
typedef __attribute__((ext_vector_type(4))) float f32x4;

__device__ __forceinline__ float bf2f(unsigned short u) {
    return __uint_as_float((uint)u << 16);
}
__device__ __forceinline__ unsigned short f2bf(float f) {   // RTNE
    uint u = __float_as_uint(f);
    return (unsigned short)((u + 0x7FFFu + ((u >> 16) & 1u)) >> 16);
}

// async global->LDS, 16B per lane; LDS dest = wave-uniform base + lane*16
__device__ __forceinline__ void gload16(const unsigned short* g, unsigned short* l) {
    __builtin_amdgcn_global_load_lds(
        (const __attribute__((address_space(1))) void*)g,
        (__attribute__((address_space(3))) void*)l, 16, 0, 0);
}

// accumulate 8 bf16 of a uint4 into acc[8]
__device__ __forceinline__ void acc_u4(float* a, uint4 v) {
    a[0] += bf2f((unsigned short)(v.x & 0xFFFF)); a[1] += bf2f((unsigned short)(v.x >> 16));
    a[2] += bf2f((unsigned short)(v.y & 0xFFFF)); a[3] += bf2f((unsigned short)(v.y >> 16));
    a[4] += bf2f((unsigned short)(v.z & 0xFFFF)); a[5] += bf2f((unsigned short)(v.z >> 16));
    a[6] += bf2f((unsigned short)(v.w & 0xFFFF)); a[7] += bf2f((unsigned short)(v.w >> 16));
}
__device__ __forceinline__ void acc_u4m(float* a, uint4 v, float m) {
    a[0] += m * bf2f((unsigned short)(v.x & 0xFFFF)); a[1] += m * bf2f((unsigned short)(v.x >> 16));
    a[2] += m * bf2f((unsigned short)(v.y & 0xFFFF)); a[3] += m * bf2f((unsigned short)(v.y >> 16));
    a[4] += m * bf2f((unsigned short)(v.z & 0xFFFF)); a[5] += m * bf2f((unsigned short)(v.z >> 16));
    a[6] += m * bf2f((unsigned short)(v.w & 0xFFFF)); a[7] += m * bf2f((unsigned short)(v.w >> 16));
}

// ---------------------------------------------------------------- prep: zero + cast + WT
// blocks [0, 6250): cast x -> bf16 XB
// blocks [6250, 6446): zero deg (and tickets in first block)
// blocks [6446, 6526): weight transpose for all 3 layers
__global__ __launch_bounds__(256) void prep_kernel(
    const float* __restrict__ x, unsigned short* __restrict__ xb,
    const float* __restrict__ Wn0, const float* __restrict__ Wr0, unsigned short* __restrict__ WT0,
    const float* __restrict__ Wn1, const float* __restrict__ Wr1, unsigned short* __restrict__ WT1,
    const float* __restrict__ Wn2, const float* __restrict__ Wr2, unsigned short* __restrict__ WT2,
    int* __restrict__ deg, int* __restrict__ tickets) {
    int bb = blockIdx.x;
    if (bb < CAST_BLOCKS) {
        int i = bb * 256 + threadIdx.x;     // < 1,600,000 exact
        float4 v = *(const float4*)&x[(long)i * 4];
        unsigned short o[4] = {f2bf(v.x), f2bf(v.y), f2bf(v.z), f2bf(v.w)};
        *(uint2*)&xb[(long)i * 4] = *(const uint2*)o;
    } else if (bb < CAST_BLOCKS + SCAN_BLOCKS) {
        int i = (bb - CAST_BLOCKS) * 256 + threadIdx.x;
        if (i < N_NODES) deg[i] = 0;
        if (bb == CAST_BLOCKS && threadIdx.x < 3) tickets[threadIdx.x] = 0;
    } else {
        int wb = bb - (CAST_BLOCKS + SCAN_BLOCKS);   // 0..79
        const float* Wn; const float* Wr; unsigned short* WT; int K1, KT, kb;
        if (wb < 16)      { Wn = Wn0; Wr = Wr0; WT = WT0; K1 = F_IN; KT = 2 * F_IN; kb = wb; }
        else if (wb < 48) { Wn = Wn1; Wr = Wr1; WT = WT1; K1 = HID;  KT = 2 * HID;  kb = wb - 16; }
        else              { Wn = Wn2; Wr = Wr2; WT = WT2; K1 = HID;  KT = 2 * HID;  kb = wb - 48; }
        int n  = threadIdx.x;
        int k0 = kb * 16;
        unsigned short o[16];
#pragma unroll
        for (int j = 0; j < 16; ++j) {
            int k = k0 + j;
            float v = (k < K1) ? Wn[k * HID + n] : Wr[(k - K1) * HID + n];
            o[j] = f2bf(v);
        }
        *(uint4*)&WT[(long)n * KT + k0]     = *(const uint4*)&o[0];
        *(uint4*)&WT[(long)n * KT + k0 + 8] = *(const uint4*)&o[8];
    }
}

// ---------------------------------------------------------------- CSR build
// hist also records each edge's rank among same-dst edges -> fill needs no atomic.
__global__ void hist_kernel(const int* __restrict__ dst, int* __restrict__ deg,
                            int* __restrict__ rank) {
    int e = blockIdx.x * blockDim.x + threadIdx.x;
    if (e < N_EDGES) rank[e] = atomicAdd(&deg[dst[e]], 1);
}

__global__ __launch_bounds__(256) void scan1_kernel(const int* __restrict__ deg,
                                                    int* __restrict__ row_ptr,
                                                    int* __restrict__ partials) {
    __shared__ int sm[256];
    int i = blockIdx.x * 256 + threadIdx.x;
    int v = (i < N_NODES) ? deg[i] : 0;
    sm[threadIdx.x] = v;
    __syncthreads();
    for (int off = 1; off < 256; off <<= 1) {
        int t = (threadIdx.x >= off) ? sm[threadIdx.x - off] : 0;
        __syncthreads();
        sm[threadIdx.x] += t;
        __syncthreads();
    }
    if (i < N_NODES) row_ptr[i] = sm[threadIdx.x] - v;   // tile-local exclusive
    if (threadIdx.x == 255) partials[blockIdx.x] = sm[255];
}

// scan2 folded in: each block reduces partials[0..b-1] itself (196 values).
__global__ __launch_bounds__(256) void scan3_kernel(int* __restrict__ row_ptr,
                                                    const int* __restrict__ partials) {
    __shared__ int red[4];
    int t = threadIdx.x;
    int v = (t < SCAN_BLOCKS && t < (int)blockIdx.x) ? partials[t] : 0;
#pragma unroll
    for (int off = 32; off; off >>= 1) v += __shfl_down(v, off);
    if ((t & 63) == 0) red[t >> 6] = v;
    __syncthreads();
    int base = red[0] + red[1] + red[2] + red[3];
    int i = blockIdx.x * 256 + t;
    if (i < N_NODES) row_ptr[i] += base;
    if (i == 0) row_ptr[N_NODES] = N_EDGES;
}

// atomic-free fill: position = row_ptr[dst] + rank
__global__ void fill_kernel(const int* __restrict__ src, const int* __restrict__ dst,
                            const int* __restrict__ rank, const int* __restrict__ row_ptr,
                            int* __restrict__ csr_src) {
    int e = blockIdx.x * blockDim.x + threadIdx.x;
    if (e >= N_EDGES) return;
    int pos = row_ptr[dst[e]] + rank[e];
    __builtin_nontemporal_store(src[e], &csr_src[pos]);
}

// ---------------------------------------------------------------- gather-mean (bf16)
// uint4 (16B/lane) loads; 16-edge unrolled groups keep 8 (D=256) / 4 (D=128)
// independent 16B loads in flight per thread (latency-bound kernel).
template<int D>
__global__ __launch_bounds__(256) void gather_mean_kernel(
    const unsigned short* __restrict__ x, const int* __restrict__ row_ptr,
    const int* __restrict__ csr_src, unsigned short* __restrict__ agg) {
    int node = blockIdx.x * 4 + (threadIdx.x >> 6);
    int lane = threadIdx.x & 63;
    if (node >= N_NODES) return;
    int beg = row_ptr[node], end = row_ptr[node + 1];
    float acc[8];
#pragma unroll
    for (int j = 0; j < 8; j++) acc[j] = 0.f;
    int e = beg;

    if constexpr (D == 256) {
        const int half = lane >> 5;          // which edge of the pair
        const long lo  = (long)(lane & 31) * 8;
        for (; e + 16 <= end; e += 16) {
            int s0 = csr_src[e + half],      s1 = csr_src[e + 2 + half];
            int s2 = csr_src[e + 4 + half],  s3 = csr_src[e + 6 + half];
            int s4 = csr_src[e + 8 + half],  s5 = csr_src[e + 10 + half];
            int s6 = csr_src[e + 12 + half], s7 = csr_src[e + 14 + half];
            uint4 v0 = *(const uint4*)&x[(long)s0 * 256 + lo];
            uint4 v1 = *(const uint4*)&x[(long)s1 * 256 + lo];
            uint4 v2 = *(const uint4*)&x[(long)s2 * 256 + lo];
            uint4 v3 = *(const uint4*)&x[(long)s3 * 256 + lo];
            uint4 v4 = *(const uint4*)&x[(long)s4 * 256 + lo];
            uint4 v5 = *(const uint4*)&x[(long)s5 * 256 + lo];
            uint4 v6 = *(const uint4*)&x[(long)s6 * 256 + lo];
            uint4 v7 = *(const uint4*)&x[(long)s7 * 256 + lo];
            acc_u4(acc, v0); acc_u4(acc, v1); acc_u4(acc, v2); acc_u4(acc, v3);
            acc_u4(acc, v4); acc_u4(acc, v5); acc_u4(acc, v6); acc_u4(acc, v7);
        }
        for (; e + 8 <= end; e += 8) {
            int s0 = csr_src[e + half],     s1 = csr_src[e + 2 + half];
            int s2 = csr_src[e + 4 + half], s3 = csr_src[e + 6 + half];
            uint4 v0 = *(const uint4*)&x[(long)s0 * 256 + lo];
            uint4 v1 = *(const uint4*)&x[(long)s1 * 256 + lo];
            uint4 v2 = *(const uint4*)&x[(long)s2 * 256 + lo];
            uint4 v3 = *(const uint4*)&x[(long)s3 * 256 + lo];
            acc_u4(acc, v0); acc_u4(acc, v1); acc_u4(acc, v2); acc_u4(acc, v3);
        }
        for (; e + 2 <= end; e += 2) {
            int s0 = csr_src[e + half];
            uint4 v0 = *(const uint4*)&x[(long)s0 * 256 + lo];
            acc_u4(acc, v0);
        }
        if (e < end) {                        // single tail edge: mask half 1
            int s0 = csr_src[e];
            uint4 v0 = *(const uint4*)&x[(long)s0 * 256 + lo];
            acc_u4m(acc, v0, (half == 0) ? 1.f : 0.f);
        }
#pragma unroll
        for (int j = 0; j < 8; j++) acc[j] += __shfl_xor(acc[j], 32);
        float inv = 1.0f / fmaxf((float)(end - beg), 1.0f);
        if (half == 0) {
            unsigned short ov[8];
#pragma unroll
            for (int j = 0; j < 8; j++) ov[j] = f2bf(acc[j] * inv);
            *(uint4*)&agg[(long)node * 256 + lo] = *(const uint4*)ov;
        }
    } else {   // D == 128
        const int grp = lane >> 4;           // which edge of the quad
        const long lo = (long)(lane & 15) * 8;
        for (; e + 16 <= end; e += 16) {
            int sA = csr_src[e + grp],     sB = csr_src[e + 4 + grp];
            int sC = csr_src[e + 8 + grp], sD = csr_src[e + 12 + grp];
            uint4 vA = *(const uint4*)&x[(long)sA * 128 + lo];
            uint4 vB = *(const uint4*)&x[(long)sB * 128 + lo];
            uint4 vC = *(const uint4*)&x[(long)sC * 128 + lo];
            uint4 vD = *(const uint4*)&x[(long)sD * 128 + lo];
            acc_u4(acc, vA); acc_u4(acc, vB); acc_u4(acc, vC); acc_u4(acc, vD);
        }
        for (; e + 8 <= end; e += 8) {
            int sA = csr_src[e + grp], sB = csr_src[e + 4 + grp];
            uint4 vA = *(const uint4*)&x[(long)sA * 128 + lo];
            uint4 vB = *(const uint4*)&x[(long)sB * 128 + lo];
            acc_u4(acc, vA); acc_u4(acc, vB);
        }
        for (; e + 4 <= end; e += 4) {
            int sA = csr_src[e + grp];
            uint4 vA = *(const uint4*)&x[(long)sA * 128 + lo];
            acc_u4(acc, vA);
        }
        for (; e < end; e++) {                // up to 3 tail edges: mask grp>0
            int s0 = csr_src[e];
            uint4 v0 = *(const uint4*)&x[(long)s0 * 128 + lo];
            acc_u4m(acc, v0, (grp == 0) ? 1.f : 0.f);
        }
#pragma unroll
        for (int j = 0; j < 8; j++) {
            acc[j] += __shfl_xor(acc[j], 32);
            acc[j] += __shfl_xor(acc[j], 16);
        }
        float inv = 1.0f / fmaxf((float)(end - beg), 1.0f);
        if (lane < 16) {
            unsigned short ov[8];
#pragma unroll
            for (int j = 0; j < 8; j++) ov[j] = f2bf(acc[j] * inv);
            *(uint4*)&agg[(long)node * 128 + lo] = *(const uint4*)ov;
        }
    }
}

// ---------------------------------------------------------------- MFMA GEMM + BN stats
// 256x256 tile per block, 512 threads (8 waves, 2M x 4N), BK=64 double-buffered
// 128 KB LDS, counted-vmcnt prefetch. BN column partials -> plain stores; the
// LAST block (device-scope ticket, split-K pattern -- no grid sync, no cross-XCD
// L2 invalidate storm) reduces the 392x512 partials and writes scale/shift ss.
template<int K1, int K2>
__global__ __launch_bounds__(512) void mfma_gemm_kernel(
    const unsigned short* __restrict__ A1, const unsigned short* __restrict__ A2,
    const unsigned short* __restrict__ WT, const float* __restrict__ bias,
    const float* __restrict__ gam, const float* __restrict__ bet,
    unsigned short* __restrict__ Hout, float* __restrict__ sred,
    float* __restrict__ ss, int* __restrict__ ticket) {
    constexpr int KT = K1 + K2;
    constexpr int NITER = KT / 64;
    constexpr int NROWS = 2 * RB256;             // 392 partial rows
    __shared__ unsigned short As[2][256 * 64];   // 2 x 32 KB, chunk-swizzled
    __shared__ unsigned short Bs[2][256 * 64];   // 2 x 32 KB, chunk-swizzled
    __shared__ float qsm[256];
    __shared__ int lastflag;

    const int tid  = threadIdx.x;
    const int wave = tid >> 6;                // 0..7
    const int lane = tid & 63;
    const int m16  = lane & 15;
    const int quad = lane >> 4;
    const int WR   = wave >> 2;               // 0..1 (row 128-half)
    const int WC   = wave & 3;                // 0..3 (col 64-quarter)
    const int r0   = blockIdx.x * 256;
    const int rl = lane >> 3;                 // staging: row within 8-group
    const int cl = lane & 7;                  // staging: logical chunk
    const int csw = cl ^ rl;                  // swizzled chunk fetched by this lane

    f32x4 acc[8][4];
#pragma unroll
    for (int mt = 0; mt < 8; mt++)
#pragma unroll
        for (int nt = 0; nt < 4; nt++) acc[mt][nt] = (f32x4){0.f, 0.f, 0.f, 0.f};

    // issue one 64-k tile's 8 global_load_lds per wave (4 A + 4 B) into buf t&1
    auto issue = [&](int t) {
        const int buf = t & 1;
        const int k0  = t * 64;
        const unsigned short* Ab;
        int pitch, kk;
        if (k0 < K1) { Ab = A1; pitch = K1; kk = k0; }
        else         { Ab = A2; pitch = K2; kk = k0 - K1; }
#pragma unroll
        for (int j = 0; j < 4; ++j) {
            int lr = wave * 32 + j * 8 + rl;
            long gr = min(r0 + lr, N_NODES - 1);
            gload16(&Ab[gr * pitch + kk + csw * 8], &As[buf][(wave * 32 + j * 8) * 64]);
        }
#pragma unroll
        for (int j = 0; j < 4; ++j) {
            long gn = wave * 32 + j * 8 + rl;   // B rows = output cols 0..255
            gload16(&WT[gn * KT + k0 + csw * 8], &Bs[buf][(wave * 32 + j * 8) * 64]);
        }
    };

    issue(0);

#pragma unroll
    for (int it = 0; it < NITER; ++it) {
        const int cur = it & 1;
        if (it + 1 < NITER) {
            issue(it + 1);                                   // 8 new loads in flight
            asm volatile("s_waitcnt vmcnt(8)" ::: "memory"); // tile it retired; it+1 stays out
        } else {
            asm volatile("s_waitcnt vmcnt(0)" ::: "memory");
        }
        __builtin_amdgcn_s_barrier();                        // tile it visible block-wide
#pragma unroll
        for (int ks = 0; ks < 2; ++ks) {
            bf16x8 afrag[8], bfrag[4];
#pragma unroll
            for (int mt = 0; mt < 8; mt++) {
                int ar = WR * 128 + mt * 16 + m16;
                afrag[mt] = *(const bf16x8*)&As[cur][ar * 64 + (((ks * 4 + quad) ^ (m16 & 7)) * 8)];
            }
#pragma unroll
            for (int nt = 0; nt < 4; nt++) {
                int br = WC * 64 + nt * 16 + m16;
                bfrag[nt] = *(const bf16x8*)&Bs[cur][br * 64 + (((ks * 4 + quad) ^ (m16 & 7)) * 8)];
            }
#pragma unroll
            for (int mt = 0; mt < 8; mt++)
#pragma unroll
                for (int nt = 0; nt < 4; nt++)
                    acc[mt][nt] = __builtin_amdgcn_mfma_f32_16x16x32_bf16(
                        afrag[mt], bfrag[nt], acc[mt][nt], 0, 0, 0);
        }
        __builtin_amdgcn_s_barrier();                        // buffer cur free next iter
    }

    // epilogue: C/D layout col=lane&15, row=quad*4+reg; BN partials, plain stores
#pragma unroll
    for (int nt = 0; nt < 4; nt++) {
        int lcol = WC * 64 + nt * 16 + m16;
        float bv = bias[lcol];
        float s = 0.f, q = 0.f;
#pragma unroll
        for (int mt = 0; mt < 8; mt++) {
#pragma unroll
            for (int reg = 0; reg < 4; reg++) {
                int row = r0 + WR * 128 + mt * 16 + quad * 4 + reg;
                float v = acc[mt][nt][reg] + bv;
                if (row < N_NODES) {
                    Hout[(long)row * HID + lcol] = f2bf(v);
                    s += v;
                    q += v * v;
                }
            }
        }
        s += __shfl_xor(s, 16); s += __shfl_xor(s, 32);
        q += __shfl_xor(q, 16); q += __shfl_xor(q, 32);
        if (quad == 0) {
            float* base = &sred[(long)(blockIdx.x * 2 + WR) * 512];
            base[lcol]       = s;
            base[256 + lcol] = q;
        }
    }

    // last-block reduce -> per-channel scale/shift (split-K ticket pattern)
    __threadfence();                                   // release sred stores
    __syncthreads();
    if (tid == 0) lastflag = (atomicAdd(ticket, 1) == (int)gridDim.x - 1) ? 1 : 0;
    __syncthreads();
    if (!lastflag) return;
    __threadfence();                                   // acquire other blocks' sred
    {
        int off = (tid < 256) ? 0 : 256;
        int ch  = tid & 255;
        float S0 = 0.f, S1 = 0.f, S2 = 0.f, S3 = 0.f;
#pragma unroll 1
        for (int rb = 0; rb < NROWS; rb += 4) {
            S0 += sred[(long)(rb + 0) * 512 + off + ch];
            S1 += sred[(long)(rb + 1) * 512 + off + ch];
            S2 += sred[(long)(rb + 2) * 512 + off + ch];
            S3 += sred[(long)(rb + 3) * 512 + off + ch];
        }
        float Sv = (S0 + S1) + (S2 + S3);
        if (tid >= 256) qsm[ch] = Sv;
        __syncthreads();
        if (tid < 256) {
            float mu  = Sv * (1.0f / N_NODES);
            float var = qsm[ch] * (1.0f / N_NODES) - mu * mu;
            var = fmaxf(var, 0.f);
            float sc = rsqrtf(var + BN_EPS) * gam[ch];
            ss[ch]       = sc;
            ss[HID + ch] = bet[ch] - mu * sc;
        }
    }
}

// ---------------------------------------------------------------- BN + ELU
template<bool OUT32>
__global__ void bn_elu_kernel(const unsigned short* __restrict__ h, const float* __restrict__ ss,
                              void* __restrict__ out) {
    const int total4 = N_NODES * HID / 4;
    int i = blockIdx.x * blockDim.x + threadIdx.x;
    if (i >= total4) return;
    int c4 = (i % (HID / 4)) * 4;
    uint2 v = *(const uint2*)&h[(long)i * 4];
    float4 sc = *(const float4*)&ss[c4];
    float4 sh = *(const float4*)&ss[HID + c4];
    float in[4] = {bf2f((unsigned short)(v.x & 0xFFFF)), bf2f((unsigned short)(v.x >> 16)),
                   bf2f((unsigned short)(v.y & 0xFFFF)), bf2f((unsigned short)(v.y >> 16))};
    float scv[4] = {sc.x, sc.y, sc.z, sc.w};
    float shv[4] = {sh.x, sh.y, sh.z, sh.w};
    float o[4];
#pragma unroll
    for (int j = 0; j < 4; j++) {
        float t = fmaf(in[j], scv[j], shv[j]);
        o[j] = t > 0.f ? t : expm1f(t);
    }
    if (OUT32) {
        float4 ov = {o[0], o[1], o[2], o[3]};
        *(float4*)&((float*)out)[(long)i * 4] = ov;
    } else {
        unsigned short ov[4] = {f2bf(o[0]), f2bf(o[1]), f2bf(o[2]), f2bf(o[3])};
        *(uint2*)&((unsigned short*)out)[(long)i * 4] = *(const uint2*)ov;
    }
}

// ---------------------------------------------------------------- launch
extern "C" void kernel_launch(void* const* d_in, const int* in_sizes, int n_in,
                              void* d_out, int out_size, void* d_ws, size_t ws_size,
                              hipStream_t stream) {
    const float* x   = (const float*)d_in[0];
    const int*   ei  = (const int*)d_in[1];
    const int*   src = ei;
    const int*   dst = ei + N_EDGES;
    const float* Wn[3] = {(const float*)d_in[2],  (const float*)d_in[7],  (const float*)d_in[12]};
    const float* bn[3] = {(const float*)d_in[3],  (const float*)d_in[8],  (const float*)d_in[13]};
    const float* Wr[3] = {(const float*)d_in[4],  (const float*)d_in[9],  (const float*)d_in[14]};
    const float* g [3] = {(const float*)d_in[5],  (const float*)d_in[10], (const float*)d_in[15]};
    const float* b [3] = {(const float*)d_in[6],  (const float*)d_in[11], (const float*)d_in[16]};
    float* out = (float*)d_out;

    const size_t BF = (size_t)N_NODES * HID * 2;   // 25.6 MB (bf16 N x 256)
    char* ws = (char*)d_ws;
    unsigned short* B0  = (unsigned short*)(ws);                  // agg bf16
    unsigned short* B1  = (unsigned short*)(ws + BF);             // gemm out bf16
    unsigned short* B2  = (unsigned short*)(ws + 2 * BF);         // activations bf16
    unsigned short* XB  = (unsigned short*)(ws + 3 * BF);         // x bf16 [N,128] 12.8 MB
    char* ws2 = ws + 3 * BF + (size_t)N_NODES * F_IN * 2;
    unsigned short* WT0 = (unsigned short*)(ws2);                 // [256][256]
    unsigned short* WT1 = (unsigned short*)(ws2 + 256 * 256 * 2); // [256][512]
    unsigned short* WT2 = (unsigned short*)(ws2 + 256 * 256 * 2 + 256 * 512 * 2);
    char* ws3 = ws2 + 256 * 256 * 2 + 2 * (256 * 512 * 2);
    int*   row_ptr = (int*)ws3;
    int*   deg_i   = row_ptr + (N_NODES + 1);
    int*   partial = deg_i + N_NODES;
    int*   rank    = partial + SCAN_BLOCKS;
    int*   csr_src = rank + N_EDGES;
    int*   tickets = csr_src + N_EDGES;
    float* sred    = (float*)(tickets + 4);              // [2*RB256][512] partials
    float* ss      = sred + (size_t)2 * RB256 * 512;     // 2*HID scale/shift

    const int eb = (N_EDGES + 255) / 256;
    const int gather_blocks = (N_NODES + 3) / 4;
    const int elu_blocks = (N_NODES * HID / 4 + 255) / 256;
    const int prep_blocks = CAST_BLOCKS + SCAN_BLOCKS + WT_BLOCKS;

    // ---------------- one-time per call: prep + CSR (5 dispatches, no memset)
    prep_kernel<<<prep_blocks, 256, 0, stream>>>(x, XB,
        Wn[0], Wr[0], WT0, Wn[1], Wr[1], WT1, Wn[2], Wr[2], WT2, deg_i, tickets);
    hist_kernel<<<eb, 256, 0, stream>>>(dst, deg_i, rank);
    scan1_kernel<<<SCAN_BLOCKS, 256, 0, stream>>>(deg_i, row_ptr, partial);
    scan3_kernel<<<SCAN_BLOCKS, 256, 0, stream>>>(row_ptr, partial);
    fill_kernel<<<eb, 256, 0, stream>>>(src, dst, rank, row_ptr, csr_src);

    // ---------------- layer 0: XB[N,128] -> act B2
    gather_mean_kernel<F_IN><<<gather_blocks, 256, 0, stream>>>(XB, row_ptr, csr_src, B0);
    mfma_gemm_kernel<F_IN, F_IN><<<RB256, 512, 0, stream>>>(B0, XB, WT0, bn[0], g[0], b[0],
                                                            B1, sred, ss, &tickets[0]);
    bn_elu_kernel<false><<<elu_blocks, 256, 0, stream>>>(B1, ss, B2);

    // ---------------- layer 1: B2 -> act B2
    gather_mean_kernel<HID><<<gather_blocks, 256, 0, stream>>>(B2, row_ptr, csr_src, B0);
    mfma_gemm_kernel<HID, HID><<<RB256, 512, 0, stream>>>(B0, B2, WT1, bn[1], g[1], b[1],
                                                          B1, sred, ss, &tickets[1]);
    bn_elu_kernel<false><<<elu_blocks, 256, 0, stream>>>(B1, ss, B2);

    // ---------------- layer 2: B2 -> out (fp32)
    gather_mean_kernel<HID><<<gather_blocks, 256, 0, stream>>>(B2, row_ptr, csr_src, B0);
    mfma_gemm_kernel<HID, HID><<<RB256, 512, 0, stream>>>(B0, B2, WT2, bn[2], g[2], b[2],
                                                          B1, sred, ss, &tickets[2]);
    bn_elu_kernel<true><<<elu_blocks, 256, 0, stream>>>(B1, ss, out);
}

// Round 7
// 545.599 us; speedup vs baseline: 1.2785x; 1.2145x over previous
//
#include <hip/hip_runtime.h>
#include <math.h>

#define N_NODES 50000
#define N_EDGES 800000
#define F_IN    128
#define HID     256
#define BN_EPS  1e-5f
#define SCAN_BLOCKS ((N_NODES + 255) / 256)   // 196
#define RB256       ((N_NODES + 255) / 256)   // 196 gemm row-blocks
#define CAST_BLOCKS (N_NODES * F_IN / 4 / 256) // 6250 exact
#define WT_BLOCKS   (16 + 32 + 32)             // 80

typedef unsigned int uint;
typedef __attribute__((ext_vector_type(8))) short bf16x8;  // 8 bf16 = 4 VGPRs
typedef __attribute__((ext_vector_type(4))) float f32x4;

__device__ __forceinline__ float bf2f(unsigned short u) {
    return __uint_as_float((uint)u << 16);
}
__device__ __forceinline__ unsigned short f2bf(float f) {   // RTNE
    uint u = __float_as_uint(f);
    return (unsigned short)((u + 0x7FFFu + ((u >> 16) & 1u)) >> 16);
}

// async global->LDS, 16B per lane; LDS dest = wave-uniform base + lane*16
__device__ __forceinline__ void gload16(const unsigned short* g, unsigned short* l) {
    __builtin_amdgcn_global_load_lds(
        (const __attribute__((address_space(1))) void*)g,
        (__attribute__((address_space(3))) void*)l, 16, 0, 0);
}

// accumulate 8 bf16 of a uint4 into acc[8]
__device__ __forceinline__ void acc_u4(float* a, uint4 v) {
    a[0] += bf2f((unsigned short)(v.x & 0xFFFF)); a[1] += bf2f((unsigned short)(v.x >> 16));
    a[2] += bf2f((unsigned short)(v.y & 0xFFFF)); a[3] += bf2f((unsigned short)(v.y >> 16));
    a[4] += bf2f((unsigned short)(v.z & 0xFFFF)); a[5] += bf2f((unsigned short)(v.z >> 16));
    a[6] += bf2f((unsigned short)(v.w & 0xFFFF)); a[7] += bf2f((unsigned short)(v.w >> 16));
}
__device__ __forceinline__ void acc_u4m(float* a, uint4 v, float m) {
    a[0] += m * bf2f((unsigned short)(v.x & 0xFFFF)); a[1] += m * bf2f((unsigned short)(v.x >> 16));
    a[2] += m * bf2f((unsigned short)(v.y & 0xFFFF)); a[3] += m * bf2f((unsigned short)(v.y >> 16));
    a[4] += m * bf2f((unsigned short)(v.z & 0xFFFF)); a[5] += m * bf2f((unsigned short)(v.z >> 16));
    a[6] += m * bf2f((unsigned short)(v.w & 0xFFFF)); a[7] += m * bf2f((unsigned short)(v.w >> 16));
}

// ---------------------------------------------------------------- prep: zero + cast + WT
// blocks [0, 6250): cast x -> bf16 XB
// blocks [6250, 6446): zero deg
// blocks [6446, 6526): weight transpose for all 3 layers
__global__ __launch_bounds__(256) void prep_kernel(
    const float* __restrict__ x, unsigned short* __restrict__ xb,
    const float* __restrict__ Wn0, const float* __restrict__ Wr0, unsigned short* __restrict__ WT0,
    const float* __restrict__ Wn1, const float* __restrict__ Wr1, unsigned short* __restrict__ WT1,
    const float* __restrict__ Wn2, const float* __restrict__ Wr2, unsigned short* __restrict__ WT2,
    int* __restrict__ deg) {
    int bb = blockIdx.x;
    if (bb < CAST_BLOCKS) {
        int i = bb * 256 + threadIdx.x;     // < 1,600,000 exact
        float4 v = *(const float4*)&x[(long)i * 4];
        unsigned short o[4] = {f2bf(v.x), f2bf(v.y), f2bf(v.z), f2bf(v.w)};
        *(uint2*)&xb[(long)i * 4] = *(const uint2*)o;
    } else if (bb < CAST_BLOCKS + SCAN_BLOCKS) {
        int i = (bb - CAST_BLOCKS) * 256 + threadIdx.x;
        if (i < N_NODES) deg[i] = 0;
    } else {
        int wb = bb - (CAST_BLOCKS + SCAN_BLOCKS);   // 0..79
        const float* Wn; const float* Wr; unsigned short* WT; int K1, KT, kb;
        if (wb < 16)      { Wn = Wn0; Wr = Wr0; WT = WT0; K1 = F_IN; KT = 2 * F_IN; kb = wb; }
        else if (wb < 48) { Wn = Wn1; Wr = Wr1; WT = WT1; K1 = HID;  KT = 2 * HID;  kb = wb - 16; }
        else              { Wn = Wn2; Wr = Wr2; WT = WT2; K1 = HID;  KT = 2 * HID;  kb = wb - 48; }
        int n  = threadIdx.x;
        int k0 = kb * 16;
        unsigned short o[16];
#pragma unroll
        for (int j = 0; j < 16; ++j) {
            int k = k0 + j;
            float v = (k < K1) ? Wn[k * HID + n] : Wr[(k - K1) * HID + n];
            o[j] = f2bf(v);
        }
        *(uint4*)&WT[(long)n * KT + k0]     = *(const uint4*)&o[0];
        *(uint4*)&WT[(long)n * KT + k0 + 8] = *(const uint4*)&o[8];
    }
}

// ---------------------------------------------------------------- CSR build
// hist also records each edge's rank among same-dst edges -> fill needs no atomic.
__global__ void hist_kernel(const int* __restrict__ dst, int* __restrict__ deg,
                            int* __restrict__ rank) {
    int e = blockIdx.x * blockDim.x + threadIdx.x;
    if (e < N_EDGES) rank[e] = atomicAdd(&deg[dst[e]], 1);
}

__global__ __launch_bounds__(256) void scan1_kernel(const int* __restrict__ deg,
                                                    int* __restrict__ row_ptr,
                                                    int* __restrict__ partials) {
    __shared__ int sm[256];
    int i = blockIdx.x * 256 + threadIdx.x;
    int v = (i < N_NODES) ? deg[i] : 0;
    sm[threadIdx.x] = v;
    __syncthreads();
    for (int off = 1; off < 256; off <<= 1) {
        int t = (threadIdx.x >= off) ? sm[threadIdx.x - off] : 0;
        __syncthreads();
        sm[threadIdx.x] += t;
        __syncthreads();
    }
    if (i < N_NODES) row_ptr[i] = sm[threadIdx.x] - v;   // tile-local exclusive
    if (threadIdx.x == 255) partials[blockIdx.x] = sm[255];
}

// scan2 folded in: each block reduces partials[0..b-1] itself (196 values).
__global__ __launch_bounds__(256) void scan3_kernel(int* __restrict__ row_ptr,
                                                    const int* __restrict__ partials) {
    __shared__ int red[4];
    int t = threadIdx.x;
    int v = (t < SCAN_BLOCKS && t < (int)blockIdx.x) ? partials[t] : 0;
#pragma unroll
    for (int off = 32; off; off >>= 1) v += __shfl_down(v, off);
    if ((t & 63) == 0) red[t >> 6] = v;
    __syncthreads();
    int base = red[0] + red[1] + red[2] + red[3];
    int i = blockIdx.x * 256 + t;
    if (i < N_NODES) row_ptr[i] += base;
    if (i == 0) row_ptr[N_NODES] = N_EDGES;
}

// atomic-free fill: position = row_ptr[dst] + rank
__global__ void fill_kernel(const int* __restrict__ src, const int* __restrict__ dst,
                            const int* __restrict__ rank, const int* __restrict__ row_ptr,
                            int* __restrict__ csr_src) {
    int e = blockIdx.x * blockDim.x + threadIdx.x;
    if (e >= N_EDGES) return;
    int pos = row_ptr[dst[e]] + rank[e];
    __builtin_nontemporal_store(src[e], &csr_src[pos]);
}

// ---------------------------------------------------------------- gather-mean (bf16)
// uint4 (16B/lane) loads; 16-edge unrolled groups keep 8 (D=256) / 4 (D=128)
// independent 16B loads in flight per thread (latency-bound kernel).
template<int D>
__global__ __launch_bounds__(256) void gather_mean_kernel(
    const unsigned short* __restrict__ x, const int* __restrict__ row_ptr,
    const int* __restrict__ csr_src, unsigned short* __restrict__ agg) {
    int node = blockIdx.x * 4 + (threadIdx.x >> 6);
    int lane = threadIdx.x & 63;
    if (node >= N_NODES) return;
    int beg = row_ptr[node], end = row_ptr[node + 1];
    float acc[8];
#pragma unroll
    for (int j = 0; j < 8; j++) acc[j] = 0.f;
    int e = beg;

    if constexpr (D == 256) {
        const int half = lane >> 5;          // which edge of the pair
        const long lo  = (long)(lane & 31) * 8;
        for (; e + 16 <= end; e += 16) {
            int s0 = csr_src[e + half],      s1 = csr_src[e + 2 + half];
            int s2 = csr_src[e + 4 + half],  s3 = csr_src[e + 6 + half];
            int s4 = csr_src[e + 8 + half],  s5 = csr_src[e + 10 + half];
            int s6 = csr_src[e + 12 + half], s7 = csr_src[e + 14 + half];
            uint4 v0 = *(const uint4*)&x[(long)s0 * 256 + lo];
            uint4 v1 = *(const uint4*)&x[(long)s1 * 256 + lo];
            uint4 v2 = *(const uint4*)&x[(long)s2 * 256 + lo];
            uint4 v3 = *(const uint4*)&x[(long)s3 * 256 + lo];
            uint4 v4 = *(const uint4*)&x[(long)s4 * 256 + lo];
            uint4 v5 = *(const uint4*)&x[(long)s5 * 256 + lo];
            uint4 v6 = *(const uint4*)&x[(long)s6 * 256 + lo];
            uint4 v7 = *(const uint4*)&x[(long)s7 * 256 + lo];
            acc_u4(acc, v0); acc_u4(acc, v1); acc_u4(acc, v2); acc_u4(acc, v3);
            acc_u4(acc, v4); acc_u4(acc, v5); acc_u4(acc, v6); acc_u4(acc, v7);
        }
        for (; e + 8 <= end; e += 8) {
            int s0 = csr_src[e + half],     s1 = csr_src[e + 2 + half];
            int s2 = csr_src[e + 4 + half], s3 = csr_src[e + 6 + half];
            uint4 v0 = *(const uint4*)&x[(long)s0 * 256 + lo];
            uint4 v1 = *(const uint4*)&x[(long)s1 * 256 + lo];
            uint4 v2 = *(const uint4*)&x[(long)s2 * 256 + lo];
            uint4 v3 = *(const uint4*)&x[(long)s3 * 256 + lo];
            acc_u4(acc, v0); acc_u4(acc, v1); acc_u4(acc, v2); acc_u4(acc, v3);
        }
        for (; e + 2 <= end; e += 2) {
            int s0 = csr_src[e + half];
            uint4 v0 = *(const uint4*)&x[(long)s0 * 256 + lo];
            acc_u4(acc, v0);
        }
        if (e < end) {                        // single tail edge: mask half 1
            int s0 = csr_src[e];
            uint4 v0 = *(const uint4*)&x[(long)s0 * 256 + lo];
            acc_u4m(acc, v0, (half == 0) ? 1.f : 0.f);
        }
#pragma unroll
        for (int j = 0; j < 8; j++) acc[j] += __shfl_xor(acc[j], 32);
        float inv = 1.0f / fmaxf((float)(end - beg), 1.0f);
        if (half == 0) {
            unsigned short ov[8];
#pragma unroll
            for (int j = 0; j < 8; j++) ov[j] = f2bf(acc[j] * inv);
            *(uint4*)&agg[(long)node * 256 + lo] = *(const uint4*)ov;
        }
    } else {   // D == 128
        const int grp = lane >> 4;           // which edge of the quad
        const long lo = (long)(lane & 15) * 8;
        for (; e + 16 <= end; e += 16) {
            int sA = csr_src[e + grp],     sB = csr_src[e + 4 + grp];
            int sC = csr_src[e + 8 + grp], sD = csr_src[e + 12 + grp];
            uint4 vA = *(const uint4*)&x[(long)sA * 128 + lo];
            uint4 vB = *(const uint4*)&x[(long)sB * 128 + lo];
            uint4 vC = *(const uint4*)&x[(long)sC * 128 + lo];
            uint4 vD = *(const uint4*)&x[(long)sD * 128 + lo];
            acc_u4(acc, vA); acc_u4(acc, vB); acc_u4(acc, vC); acc_u4(acc, vD);
        }
        for (; e + 8 <= end; e += 8) {
            int sA = csr_src[e + grp], sB = csr_src[e + 4 + grp];
            uint4 vA = *(const uint4*)&x[(long)sA * 128 + lo];
            uint4 vB = *(const uint4*)&x[(long)sB * 128 + lo];
            acc_u4(acc, vA); acc_u4(acc, vB);
        }
        for (; e + 4 <= end; e += 4) {
            int sA = csr_src[e + grp];
            uint4 vA = *(const uint4*)&x[(long)sA * 128 + lo];
            acc_u4(acc, vA);
        }
        for (; e < end; e++) {                // up to 3 tail edges: mask grp>0
            int s0 = csr_src[e];
            uint4 v0 = *(const uint4*)&x[(long)s0 * 128 + lo];
            acc_u4m(acc, v0, (grp == 0) ? 1.f : 0.f);
        }
#pragma unroll
        for (int j = 0; j < 8; j++) {
            acc[j] += __shfl_xor(acc[j], 32);
            acc[j] += __shfl_xor(acc[j], 16);
        }
        float inv = 1.0f / fmaxf((float)(end - beg), 1.0f);
        if (lane < 16) {
            unsigned short ov[8];
#pragma unroll
            for (int j = 0; j < 8; j++) ov[j] = f2bf(acc[j] * inv);
            *(uint4*)&agg[(long)node * 128 + lo] = *(const uint4*)ov;
        }
    }
}

// ---------------------------------------------------------------- MFMA GEMM + BN partials
// 256x256 tile per block, 512 threads (8 waves, 2M x 4N), BK=64 double-buffered
// 128 KB LDS, counted-vmcnt prefetch. NO device-scope fence / ticket / grid sync
// (both cost 35-70us/dispatch on gfx950's non-coherent per-XCD L2s -- measured
// rounds 5 & 6). BN partials via plain stores; separate bn_reduce kernel.
template<int K1, int K2>
__global__ __launch_bounds__(512) void mfma_gemm_kernel(
    const unsigned short* __restrict__ A1, const unsigned short* __restrict__ A2,
    const unsigned short* __restrict__ WT, const float* __restrict__ bias,
    unsigned short* __restrict__ Hout, float* __restrict__ sred) {
    constexpr int KT = K1 + K2;
    constexpr int NITER = KT / 64;
    __shared__ unsigned short As[2][256 * 64];   // 2 x 32 KB, chunk-swizzled
    __shared__ unsigned short Bs[2][256 * 64];   // 2 x 32 KB, chunk-swizzled

    const int tid  = threadIdx.x;
    const int wave = tid >> 6;                // 0..7
    const int lane = tid & 63;
    const int m16  = lane & 15;
    const int quad = lane >> 4;
    const int WR   = wave >> 2;               // 0..1 (row 128-half)
    const int WC   = wave & 3;                // 0..3 (col 64-quarter)
    const int r0   = blockIdx.x * 256;
    const int rl = lane >> 3;                 // staging: row within 8-group
    const int cl = lane & 7;                  // staging: logical chunk
    const int csw = cl ^ rl;                  // swizzled chunk fetched by this lane

    f32x4 acc[8][4];
#pragma unroll
    for (int mt = 0; mt < 8; mt++)
#pragma unroll
        for (int nt = 0; nt < 4; nt++) acc[mt][nt] = (f32x4){0.f, 0.f, 0.f, 0.f};

    // issue one 64-k tile's 8 global_load_lds per wave (4 A + 4 B) into buf t&1
    auto issue = [&](int t) {
        const int buf = t & 1;
        const int k0  = t * 64;
        const unsigned short* Ab;
        int pitch, kk;
        if (k0 < K1) { Ab = A1; pitch = K1; kk = k0; }
        else         { Ab = A2; pitch = K2; kk = k0 - K1; }
#pragma unroll
        for (int j = 0; j < 4; ++j) {
            int lr = wave * 32 + j * 8 + rl;
            long gr = min(r0 + lr, N_NODES - 1);
            gload16(&Ab[gr * pitch + kk + csw * 8], &As[buf][(wave * 32 + j * 8) * 64]);
        }
#pragma unroll
        for (int j = 0; j < 4; ++j) {
            long gn = wave * 32 + j * 8 + rl;   // B rows = output cols 0..255
            gload16(&WT[gn * KT + k0 + csw * 8], &Bs[buf][(wave * 32 + j * 8) * 64]);
        }
    };

    issue(0);

#pragma unroll
    for (int it = 0; it < NITER; ++it) {
        const int cur = it & 1;
        if (it + 1 < NITER) {
            issue(it + 1);                                   // 8 new loads in flight
            asm volatile("s_waitcnt vmcnt(8)" ::: "memory"); // tile it retired; it+1 stays out
        } else {
            asm volatile("s_waitcnt vmcnt(0)" ::: "memory");
        }
        __builtin_amdgcn_s_barrier();                        // tile it visible block-wide
#pragma unroll
        for (int ks = 0; ks < 2; ++ks) {
            bf16x8 afrag[8], bfrag[4];
#pragma unroll
            for (int mt = 0; mt < 8; mt++) {
                int ar = WR * 128 + mt * 16 + m16;
                afrag[mt] = *(const bf16x8*)&As[cur][ar * 64 + (((ks * 4 + quad) ^ (m16 & 7)) * 8)];
            }
#pragma unroll
            for (int nt = 0; nt < 4; nt++) {
                int br = WC * 64 + nt * 16 + m16;
                bfrag[nt] = *(const bf16x8*)&Bs[cur][br * 64 + (((ks * 4 + quad) ^ (m16 & 7)) * 8)];
            }
#pragma unroll
            for (int mt = 0; mt < 8; mt++)
#pragma unroll
                for (int nt = 0; nt < 4; nt++)
                    acc[mt][nt] = __builtin_amdgcn_mfma_f32_16x16x32_bf16(
                        afrag[mt], bfrag[nt], acc[mt][nt], 0, 0, 0);
        }
        __builtin_amdgcn_s_barrier();                        // buffer cur free next iter
    }

    // epilogue: C/D layout col=lane&15, row=quad*4+reg; BN partials, plain stores
#pragma unroll
    for (int nt = 0; nt < 4; nt++) {
        int lcol = WC * 64 + nt * 16 + m16;
        float bv = bias[lcol];
        float s = 0.f, q = 0.f;
#pragma unroll
        for (int mt = 0; mt < 8; mt++) {
#pragma unroll
            for (int reg = 0; reg < 4; reg++) {
                int row = r0 + WR * 128 + mt * 16 + quad * 4 + reg;
                float v = acc[mt][nt][reg] + bv;
                if (row < N_NODES) {
                    Hout[(long)row * HID + lcol] = f2bf(v);
                    s += v;
                    q += v * v;
                }
            }
        }
        s += __shfl_xor(s, 16); s += __shfl_xor(s, 32);
        q += __shfl_xor(q, 16); q += __shfl_xor(q, 32);
        if (quad == 0) {
            float* base = &sred[(long)(blockIdx.x * 2 + WR) * 512];
            base[lcol]       = s;
            base[256 + lcol] = q;
        }
    }
}

// ---------------------------------------------------------------- BN reduce + prep
// Sums 2*RB256 per-(block,WR) partial rows; 512 threads: t<256 sum S, t>=256 sum Q.
// Kernel boundary provides the cross-XCD visibility (cheap, unlike fences).
__global__ __launch_bounds__(512) void bn_reduce_kernel(const float* __restrict__ sred,
                                                        const float* __restrict__ g,
                                                        const float* __restrict__ b,
                                                        float* __restrict__ ss, int nrows) {
    __shared__ float qsm[256];
    int t  = threadIdx.x;
    int ch = t & 255;
    int off = (t < 256) ? 0 : 256;
    float S0 = 0.f, S1 = 0.f, S2 = 0.f, S3 = 0.f;
    int rb = 0;
    for (; rb + 4 <= nrows; rb += 4) {
        S0 += sred[(long)(rb + 0) * 512 + off + ch];
        S1 += sred[(long)(rb + 1) * 512 + off + ch];
        S2 += sred[(long)(rb + 2) * 512 + off + ch];
        S3 += sred[(long)(rb + 3) * 512 + off + ch];
    }
    for (; rb < nrows; rb++) S0 += sred[(long)rb * 512 + off + ch];
    float Sv = (S0 + S1) + (S2 + S3);
    if (t >= 256) qsm[ch] = Sv;
    __syncthreads();
    if (t < 256) {
        float mu  = Sv * (1.0f / N_NODES);
        float var = qsm[ch] * (1.0f / N_NODES) - mu * mu;
        var = fmaxf(var, 0.f);
        float sc = rsqrtf(var + BN_EPS) * g[ch];
        ss[ch]       = sc;
        ss[HID + ch] = b[ch] - mu * sc;
    }
}

// ---------------------------------------------------------------- BN + ELU
template<bool OUT32>
__global__ void bn_elu_kernel(const unsigned short* __restrict__ h, const float* __restrict__ ss,
                              void* __restrict__ out) {
    const int total4 = N_NODES * HID / 4;
    int i = blockIdx.x * blockDim.x + threadIdx.x;
    if (i >= total4) return;
    int c4 = (i % (HID / 4)) * 4;
    uint2 v = *(const uint2*)&h[(long)i * 4];
    float4 sc = *(const float4*)&ss[c4];
    float4 sh = *(const float4*)&ss[HID + c4];
    float in[4] = {bf2f((unsigned short)(v.x & 0xFFFF)), bf2f((unsigned short)(v.x >> 16)),
                   bf2f((unsigned short)(v.y & 0xFFFF)), bf2f((unsigned short)(v.y >> 16))};
    float scv[4] = {sc.x, sc.y, sc.z, sc.w};
    float shv[4] = {sh.x, sh.y, sh.z, sh.w};
    float o[4];
#pragma unroll
    for (int j = 0; j < 4; j++) {
        float t = fmaf(in[j], scv[j], shv[j]);
        o[j] = t > 0.f ? t : expm1f(t);
    }
    if (OUT32) {
        float4 ov = {o[0], o[1], o[2], o[3]};
        *(float4*)&((float*)out)[(long)i * 4] = ov;
    } else {
        unsigned short ov[4] = {f2bf(o[0]), f2bf(o[1]), f2bf(o[2]), f2bf(o[3])};
        *(uint2*)&((unsigned short*)out)[(long)i * 4] = *(const uint2*)ov;
    }
}

// ---------------------------------------------------------------- launch
extern "C" void kernel_launch(void* const* d_in, const int* in_sizes, int n_in,
                              void* d_out, int out_size, void* d_ws, size_t ws_size,
                              hipStream_t stream) {
    const float* x   = (const float*)d_in[0];
    const int*   ei  = (const int*)d_in[1];
    const int*   src = ei;
    const int*   dst = ei + N_EDGES;
    const float* Wn[3] = {(const float*)d_in[2],  (const float*)d_in[7],  (const float*)d_in[12]};
    const float* bn[3] = {(const float*)d_in[3],  (const float*)d_in[8],  (const float*)d_in[13]};
    const float* Wr[3] = {(const float*)d_in[4],  (const float*)d_in[9],  (const float*)d_in[14]};
    const float* g [3] = {(const float*)d_in[5],  (const float*)d_in[10], (const float*)d_in[15]};
    const float* b [3] = {(const float*)d_in[6],  (const float*)d_in[11], (const float*)d_in[16]};
    float* out = (float*)d_out;

    const size_t BF = (size_t)N_NODES * HID * 2;   // 25.6 MB (bf16 N x 256)
    char* ws = (char*)d_ws;
    unsigned short* B0  = (unsigned short*)(ws);                  // agg bf16
    unsigned short* B1  = (unsigned short*)(ws + BF);             // gemm out bf16
    unsigned short* B2  = (unsigned short*)(ws + 2 * BF);         // activations bf16
    unsigned short* XB  = (unsigned short*)(ws + 3 * BF);         // x bf16 [N,128] 12.8 MB
    char* ws2 = ws + 3 * BF + (size_t)N_NODES * F_IN * 2;
    unsigned short* WT0 = (unsigned short*)(ws2);                 // [256][256]
    unsigned short* WT1 = (unsigned short*)(ws2 + 256 * 256 * 2); // [256][512]
    unsigned short* WT2 = (unsigned short*)(ws2 + 256 * 256 * 2 + 256 * 512 * 2);
    char* ws3 = ws2 + 256 * 256 * 2 + 2 * (256 * 512 * 2);
    int*   row_ptr = (int*)ws3;
    int*   deg_i   = row_ptr + (N_NODES + 1);
    int*   partial = deg_i + N_NODES;
    int*   rank    = partial + SCAN_BLOCKS;
    int*   csr_src = rank + N_EDGES;
    float* sred    = (float*)(csr_src + N_EDGES);        // [2*RB256][512] partials
    float* ss      = sred + (size_t)2 * RB256 * 512;     // 2*HID scale/shift

    const int eb = (N_EDGES + 255) / 256;
    const int gather_blocks = (N_NODES + 3) / 4;
    const int elu_blocks = (N_NODES * HID / 4 + 255) / 256;
    const int prep_blocks = CAST_BLOCKS + SCAN_BLOCKS + WT_BLOCKS;

    // ---------------- one-time per call: prep + CSR (5 dispatches, no memset)
    prep_kernel<<<prep_blocks, 256, 0, stream>>>(x, XB,
        Wn[0], Wr[0], WT0, Wn[1], Wr[1], WT1, Wn[2], Wr[2], WT2, deg_i);
    hist_kernel<<<eb, 256, 0, stream>>>(dst, deg_i, rank);
    scan1_kernel<<<SCAN_BLOCKS, 256, 0, stream>>>(deg_i, row_ptr, partial);
    scan3_kernel<<<SCAN_BLOCKS, 256, 0, stream>>>(row_ptr, partial);
    fill_kernel<<<eb, 256, 0, stream>>>(src, dst, rank, row_ptr, csr_src);

    // ---------------- layer 0: XB[N,128] -> act B2
    gather_mean_kernel<F_IN><<<gather_blocks, 256, 0, stream>>>(XB, row_ptr, csr_src, B0);
    mfma_gemm_kernel<F_IN, F_IN><<<RB256, 512, 0, stream>>>(B0, XB, WT0, bn[0], B1, sred);
    bn_reduce_kernel<<<1, 512, 0, stream>>>(sred, g[0], b[0], ss, 2 * RB256);
    bn_elu_kernel<false><<<elu_blocks, 256, 0, stream>>>(B1, ss, B2);

    // ---------------- layer 1: B2 -> act B2
    gather_mean_kernel<HID><<<gather_blocks, 256, 0, stream>>>(B2, row_ptr, csr_src, B0);
    mfma_gemm_kernel<HID, HID><<<RB256, 512, 0, stream>>>(B0, B2, WT1, bn[1], B1, sred);
    bn_reduce_kernel<<<1, 512, 0, stream>>>(sred, g[1], b[1], ss, 2 * RB256);
    bn_elu_kernel<false><<<elu_blocks, 256, 0, stream>>>(B1, ss, B2);

    // ---------------- layer 2: B2 -> out (fp32)
    gather_mean_kernel<HID><<<gather_blocks, 256, 0, stream>>>(B2, row_ptr, csr_src, B0);
    mfma_gemm_kernel<HID, HID><<<RB256, 512, 0, stream>>>(B0, B2, WT2, bn[2], B1, sred);
    bn_reduce_kernel<<<1, 512, 0, stream>>>(sred, g[2], b[2], ss, 2 * RB256);
    bn_elu_kernel<true><<<elu_blocks, 256, 0, stream>>>(B1, ss, out);
}

// Round 8
// 531.519 us; speedup vs baseline: 1.3124x; 1.0265x over previous
//
#include <hip/hip_runtime.h>
#include <math.h>

#define N_NODES 50000
#define N_EDGES 800000
#define F_IN    128
#define HID     256
#define BN_EPS  1e-5f
#define SCAN_BLOCKS ((N_NODES + 255) / 256)   // 196
#define RB128       ((N_NODES + 127) / 128)   // 391 gemm row-blocks
#define CAST_BLOCKS (N_NODES * F_IN / 4 / 256) // 6250 exact
#define WT_BLOCKS   (16 + 32 + 32)             // 80

typedef unsigned int uint;
typedef __attribute__((ext_vector_type(8))) short bf16x8;  // 8 bf16 = 4 VGPRs
typedef __attribute__((ext_vector_type(4))) float f32x4;

__device__ __forceinline__ float bf2f(unsigned short u) {
    return __uint_as_float((uint)u << 16);
}
__device__ __forceinline__ unsigned short f2bf(float f) {   // RTNE
    uint u = __float_as_uint(f);
    return (unsigned short)((u + 0x7FFFu + ((u >> 16) & 1u)) >> 16);
}

// async global->LDS, 16B per lane; LDS dest = wave-uniform base + lane*16
__device__ __forceinline__ void gload16(const unsigned short* g, unsigned short* l) {
    __builtin_amdgcn_global_load_lds(
        (const __attribute__((address_space(1))) void*)g,
        (__attribute__((address_space(3))) void*)l, 16, 0, 0);
}

// accumulate 8 bf16 of a uint4 into acc[8]
__device__ __forceinline__ void acc_u4(float* a, uint4 v) {
    a[0] += bf2f((unsigned short)(v.x & 0xFFFF)); a[1] += bf2f((unsigned short)(v.x >> 16));
    a[2] += bf2f((unsigned short)(v.y & 0xFFFF)); a[3] += bf2f((unsigned short)(v.y >> 16));
    a[4] += bf2f((unsigned short)(v.z & 0xFFFF)); a[5] += bf2f((unsigned short)(v.z >> 16));
    a[6] += bf2f((unsigned short)(v.w & 0xFFFF)); a[7] += bf2f((unsigned short)(v.w >> 16));
}
__device__ __forceinline__ void acc_u4m(float* a, uint4 v, float m) {
    a[0] += m * bf2f((unsigned short)(v.x & 0xFFFF)); a[1] += m * bf2f((unsigned short)(v.x >> 16));
    a[2] += m * bf2f((unsigned short)(v.y & 0xFFFF)); a[3] += m * bf2f((unsigned short)(v.y >> 16));
    a[4] += m * bf2f((unsigned short)(v.z & 0xFFFF)); a[5] += m * bf2f((unsigned short)(v.z >> 16));
    a[6] += m * bf2f((unsigned short)(v.w & 0xFFFF)); a[7] += m * bf2f((unsigned short)(v.w >> 16));
}

// ---------------------------------------------------------------- prep: zero + cast + WT
__global__ __launch_bounds__(256) void prep_kernel(
    const float* __restrict__ x, unsigned short* __restrict__ xb,
    const float* __restrict__ Wn0, const float* __restrict__ Wr0, unsigned short* __restrict__ WT0,
    const float* __restrict__ Wn1, const float* __restrict__ Wr1, unsigned short* __restrict__ WT1,
    const float* __restrict__ Wn2, const float* __restrict__ Wr2, unsigned short* __restrict__ WT2,
    int* __restrict__ deg) {
    int bb = blockIdx.x;
    if (bb < CAST_BLOCKS) {
        int i = bb * 256 + threadIdx.x;     // < 1,600,000 exact
        float4 v = *(const float4*)&x[(long)i * 4];
        unsigned short o[4] = {f2bf(v.x), f2bf(v.y), f2bf(v.z), f2bf(v.w)};
        *(uint2*)&xb[(long)i * 4] = *(const uint2*)o;
    } else if (bb < CAST_BLOCKS + SCAN_BLOCKS) {
        int i = (bb - CAST_BLOCKS) * 256 + threadIdx.x;
        if (i < N_NODES) deg[i] = 0;
    } else {
        int wb = bb - (CAST_BLOCKS + SCAN_BLOCKS);   // 0..79
        const float* Wn; const float* Wr; unsigned short* WT; int K1, KT, kb;
        if (wb < 16)      { Wn = Wn0; Wr = Wr0; WT = WT0; K1 = F_IN; KT = 2 * F_IN; kb = wb; }
        else if (wb < 48) { Wn = Wn1; Wr = Wr1; WT = WT1; K1 = HID;  KT = 2 * HID;  kb = wb - 16; }
        else              { Wn = Wn2; Wr = Wr2; WT = WT2; K1 = HID;  KT = 2 * HID;  kb = wb - 48; }
        int n  = threadIdx.x;
        int k0 = kb * 16;
        unsigned short o[16];
#pragma unroll
        for (int j = 0; j < 16; ++j) {
            int k = k0 + j;
            float v = (k < K1) ? Wn[k * HID + n] : Wr[(k - K1) * HID + n];
            o[j] = f2bf(v);
        }
        *(uint4*)&WT[(long)n * KT + k0]     = *(const uint4*)&o[0];
        *(uint4*)&WT[(long)n * KT + k0 + 8] = *(const uint4*)&o[8];
    }
}

// ---------------------------------------------------------------- CSR build
// hist also records each edge's rank among same-dst edges -> fill needs no atomic.
__global__ void hist_kernel(const int* __restrict__ dst, int* __restrict__ deg,
                            int* __restrict__ rank) {
    int e = blockIdx.x * blockDim.x + threadIdx.x;
    if (e < N_EDGES) rank[e] = atomicAdd(&deg[dst[e]], 1);
}

__global__ __launch_bounds__(256) void scan1_kernel(const int* __restrict__ deg,
                                                    int* __restrict__ row_ptr,
                                                    int* __restrict__ partials) {
    __shared__ int sm[256];
    int i = blockIdx.x * 256 + threadIdx.x;
    int v = (i < N_NODES) ? deg[i] : 0;
    sm[threadIdx.x] = v;
    __syncthreads();
    for (int off = 1; off < 256; off <<= 1) {
        int t = (threadIdx.x >= off) ? sm[threadIdx.x - off] : 0;
        __syncthreads();
        sm[threadIdx.x] += t;
        __syncthreads();
    }
    if (i < N_NODES) row_ptr[i] = sm[threadIdx.x] - v;   // tile-local exclusive
    if (threadIdx.x == 255) partials[blockIdx.x] = sm[255];
}

// scan2 folded in: each block reduces partials[0..b-1] itself (196 values).
__global__ __launch_bounds__(256) void scan3_kernel(int* __restrict__ row_ptr,
                                                    const int* __restrict__ partials) {
    __shared__ int red[4];
    int t = threadIdx.x;
    int v = (t < SCAN_BLOCKS && t < (int)blockIdx.x) ? partials[t] : 0;
#pragma unroll
    for (int off = 32; off; off >>= 1) v += __shfl_down(v, off);
    if ((t & 63) == 0) red[t >> 6] = v;
    __syncthreads();
    int base = red[0] + red[1] + red[2] + red[3];
    int i = blockIdx.x * 256 + t;
    if (i < N_NODES) row_ptr[i] += base;
    if (i == 0) row_ptr[N_NODES] = N_EDGES;
}

// atomic-free fill: position = row_ptr[dst] + rank
__global__ void fill_kernel(const int* __restrict__ src, const int* __restrict__ dst,
                            const int* __restrict__ rank, const int* __restrict__ row_ptr,
                            int* __restrict__ csr_src) {
    int e = blockIdx.x * blockDim.x + threadIdx.x;
    if (e >= N_EDGES) return;
    int pos = row_ptr[dst[e]] + rank[e];
    __builtin_nontemporal_store(src[e], &csr_src[pos]);
}

// ---------------------------------------------------------------- gather-mean (bf16)
// uint4 (16B/lane) loads; 16-edge unrolled groups keep 8 (D=256) / 4 (D=128)
// independent 16B loads in flight per thread (latency-bound kernel).
template<int D>
__global__ __launch_bounds__(256) void gather_mean_kernel(
    const unsigned short* __restrict__ x, const int* __restrict__ row_ptr,
    const int* __restrict__ csr_src, unsigned short* __restrict__ agg) {
    int node = blockIdx.x * 4 + (threadIdx.x >> 6);
    int lane = threadIdx.x & 63;
    if (node >= N_NODES) return;
    int beg = row_ptr[node], end = row_ptr[node + 1];
    float acc[8];
#pragma unroll
    for (int j = 0; j < 8; j++) acc[j] = 0.f;
    int e = beg;

    if constexpr (D == 256) {
        const int half = lane >> 5;          // which edge of the pair
        const long lo  = (long)(lane & 31) * 8;
        for (; e + 16 <= end; e += 16) {
            int s0 = csr_src[e + half],      s1 = csr_src[e + 2 + half];
            int s2 = csr_src[e + 4 + half],  s3 = csr_src[e + 6 + half];
            int s4 = csr_src[e + 8 + half],  s5 = csr_src[e + 10 + half];
            int s6 = csr_src[e + 12 + half], s7 = csr_src[e + 14 + half];
            uint4 v0 = *(const uint4*)&x[(long)s0 * 256 + lo];
            uint4 v1 = *(const uint4*)&x[(long)s1 * 256 + lo];
            uint4 v2 = *(const uint4*)&x[(long)s2 * 256 + lo];
            uint4 v3 = *(const uint4*)&x[(long)s3 * 256 + lo];
            uint4 v4 = *(const uint4*)&x[(long)s4 * 256 + lo];
            uint4 v5 = *(const uint4*)&x[(long)s5 * 256 + lo];
            uint4 v6 = *(const uint4*)&x[(long)s6 * 256 + lo];
            uint4 v7 = *(const uint4*)&x[(long)s7 * 256 + lo];
            acc_u4(acc, v0); acc_u4(acc, v1); acc_u4(acc, v2); acc_u4(acc, v3);
            acc_u4(acc, v4); acc_u4(acc, v5); acc_u4(acc, v6); acc_u4(acc, v7);
        }
        for (; e + 8 <= end; e += 8) {
            int s0 = csr_src[e + half],     s1 = csr_src[e + 2 + half];
            int s2 = csr_src[e + 4 + half], s3 = csr_src[e + 6 + half];
            uint4 v0 = *(const uint4*)&x[(long)s0 * 256 + lo];
            uint4 v1 = *(const uint4*)&x[(long)s1 * 256 + lo];
            uint4 v2 = *(const uint4*)&x[(long)s2 * 256 + lo];
            uint4 v3 = *(const uint4*)&x[(long)s3 * 256 + lo];
            acc_u4(acc, v0); acc_u4(acc, v1); acc_u4(acc, v2); acc_u4(acc, v3);
        }
        for (; e + 2 <= end; e += 2) {
            int s0 = csr_src[e + half];
            uint4 v0 = *(const uint4*)&x[(long)s0 * 256 + lo];
            acc_u4(acc, v0);
        }
        if (e < end) {                        // single tail edge: mask half 1
            int s0 = csr_src[e];
            uint4 v0 = *(const uint4*)&x[(long)s0 * 256 + lo];
            acc_u4m(acc, v0, (half == 0) ? 1.f : 0.f);
        }
#pragma unroll
        for (int j = 0; j < 8; j++) acc[j] += __shfl_xor(acc[j], 32);
        float inv = 1.0f / fmaxf((float)(end - beg), 1.0f);
        if (half == 0) {
            unsigned short ov[8];
#pragma unroll
            for (int j = 0; j < 8; j++) ov[j] = f2bf(acc[j] * inv);
            *(uint4*)&agg[(long)node * 256 + lo] = *(const uint4*)ov;
        }
    } else {   // D == 128
        const int grp = lane >> 4;           // which edge of the quad
        const long lo = (long)(lane & 15) * 8;
        for (; e + 16 <= end; e += 16) {
            int sA = csr_src[e + grp],     sB = csr_src[e + 4 + grp];
            int sC = csr_src[e + 8 + grp], sD = csr_src[e + 12 + grp];
            uint4 vA = *(const uint4*)&x[(long)sA * 128 + lo];
            uint4 vB = *(const uint4*)&x[(long)sB * 128 + lo];
            uint4 vC = *(const uint4*)&x[(long)sC * 128 + lo];
            uint4 vD = *(const uint4*)&x[(long)sD * 128 + lo];
            acc_u4(acc, vA); acc_u4(acc, vB); acc_u4(acc, vC); acc_u4(acc, vD);
        }
        for (; e + 8 <= end; e += 8) {
            int sA = csr_src[e + grp], sB = csr_src[e + 4 + grp];
            uint4 vA = *(const uint4*)&x[(long)sA * 128 + lo];
            uint4 vB = *(const uint4*)&x[(long)sB * 128 + lo];
            acc_u4(acc, vA); acc_u4(acc, vB);
        }
        for (; e + 4 <= end; e += 4) {
            int sA = csr_src[e + grp];
            uint4 vA = *(const uint4*)&x[(long)sA * 128 + lo];
            acc_u4(acc, vA);
        }
        for (; e < end; e++) {                // up to 3 tail edges: mask grp>0
            int s0 = csr_src[e];
            uint4 v0 = *(const uint4*)&x[(long)s0 * 128 + lo];
            acc_u4m(acc, v0, (grp == 0) ? 1.f : 0.f);
        }
#pragma unroll
        for (int j = 0; j < 8; j++) {
            acc[j] += __shfl_xor(acc[j], 32);
            acc[j] += __shfl_xor(acc[j], 16);
        }
        float inv = 1.0f / fmaxf((float)(end - beg), 1.0f);
        if (lane < 16) {
            unsigned short ov[8];
#pragma unroll
            for (int j = 0; j < 8; j++) ov[j] = f2bf(acc[j] * inv);
            *(uint4*)&agg[(long)node * 128 + lo] = *(const uint4*)ov;
        }
    }
}

// ---------------------------------------------------------------- MFMA GEMM + BN partials
// 128x128 tile per block, 256 threads (4 waves, 2M x 2N, each wave 64x64 output:
// acc[4][4] = 64 VGPRs -> ~116 regs/wave). BK=64 double-buffered = 64 KB LDS ->
// TWO independent blocks per CU. Rationale: every prior 1-block/CU variant pinned
// at ~50us regardless of schedule -- in a barrier-lockstepped single block the
// whole CU idles at each vmcnt+barrier; a second unsynchronized block fills the
// stall (m114 implicit wave-overlap). Counted vmcnt(8) prefetch kept.
template<int K1, int K2>
__global__ __launch_bounds__(256) void mfma_gemm_kernel(
    const unsigned short* __restrict__ A1, const unsigned short* __restrict__ A2,
    const unsigned short* __restrict__ WT, const float* __restrict__ bias,
    unsigned short* __restrict__ Hout, float* __restrict__ sred) {
    constexpr int KT = K1 + K2;
    constexpr int NITER = KT / 64;
    __shared__ unsigned short As[2][128 * 64];   // 2 x 16 KB, chunk-swizzled
    __shared__ unsigned short Bs[2][128 * 64];   // 2 x 16 KB, chunk-swizzled

    const int tid  = threadIdx.x;
    const int wave = tid >> 6;                // 0..3
    const int lane = tid & 63;
    const int m16  = lane & 15;
    const int quad = lane >> 4;
    const int WR   = wave >> 1;               // 0..1 (row 64-half)
    const int WC   = wave & 1;                // 0..1 (col 64-half)
    const int row_block = blockIdx.x >> 1;
    const int col_half  = blockIdx.x & 1;
    const int r0   = row_block * 128;
    const int rl = lane >> 3;                 // staging: row within 8-group
    const int cl = lane & 7;                  // staging: logical chunk
    const int csw = cl ^ rl;                  // swizzled chunk fetched by this lane

    f32x4 acc[4][4];
#pragma unroll
    for (int mt = 0; mt < 4; mt++)
#pragma unroll
        for (int nt = 0; nt < 4; nt++) acc[mt][nt] = (f32x4){0.f, 0.f, 0.f, 0.f};

    // issue one 64-k tile's 8 global_load_lds per wave (4 A + 4 B) into buf t&1
    auto issue = [&](int t) {
        const int buf = t & 1;
        const int k0  = t * 64;
        const unsigned short* Ab;
        int pitch, kk;
        if (k0 < K1) { Ab = A1; pitch = K1; kk = k0; }
        else         { Ab = A2; pitch = K2; kk = k0 - K1; }
#pragma unroll
        for (int j = 0; j < 4; ++j) {
            int lr = wave * 32 + j * 8 + rl;
            long gr = min(r0 + lr, N_NODES - 1);
            gload16(&Ab[gr * pitch + kk + csw * 8], &As[buf][(wave * 32 + j * 8) * 64]);
        }
#pragma unroll
        for (int j = 0; j < 4; ++j) {
            long gn = col_half * 128 + wave * 32 + j * 8 + rl;   // B rows = output cols
            gload16(&WT[gn * KT + k0 + csw * 8], &Bs[buf][(wave * 32 + j * 8) * 64]);
        }
    };

    issue(0);

#pragma unroll
    for (int it = 0; it < NITER; ++it) {
        const int cur = it & 1;
        if (it + 1 < NITER) {
            issue(it + 1);                                   // 8 new loads in flight
            asm volatile("s_waitcnt vmcnt(8)" ::: "memory"); // tile it retired; it+1 stays out
        } else {
            asm volatile("s_waitcnt vmcnt(0)" ::: "memory");
        }
        __builtin_amdgcn_s_barrier();                        // tile it visible block-wide
#pragma unroll
        for (int ks = 0; ks < 2; ++ks) {
            bf16x8 afrag[4], bfrag[4];
#pragma unroll
            for (int mt = 0; mt < 4; mt++) {
                int ar = WR * 64 + mt * 16 + m16;
                afrag[mt] = *(const bf16x8*)&As[cur][ar * 64 + (((ks * 4 + quad) ^ (m16 & 7)) * 8)];
            }
#pragma unroll
            for (int nt = 0; nt < 4; nt++) {
                int br = WC * 64 + nt * 16 + m16;
                bfrag[nt] = *(const bf16x8*)&Bs[cur][br * 64 + (((ks * 4 + quad) ^ (m16 & 7)) * 8)];
            }
#pragma unroll
            for (int mt = 0; mt < 4; mt++)
#pragma unroll
                for (int nt = 0; nt < 4; nt++)
                    acc[mt][nt] = __builtin_amdgcn_mfma_f32_16x16x32_bf16(
                        afrag[mt], bfrag[nt], acc[mt][nt], 0, 0, 0);
        }
        __builtin_amdgcn_s_barrier();                        // buffer cur free next iter
    }

    // epilogue: C/D layout col=lane&15, row=quad*4+reg; BN partials, plain stores
    // sred row = blockIdx*2 + WR, 256 wide: [0..127]=S(lcol), [128..255]=Q(lcol)
#pragma unroll
    for (int nt = 0; nt < 4; nt++) {
        int lcol = WC * 64 + nt * 16 + m16;                  // 0..127 within col_half
        int col  = col_half * 128 + lcol;
        float bv = bias[col];
        float s = 0.f, q = 0.f;
#pragma unroll
        for (int mt = 0; mt < 4; mt++) {
#pragma unroll
            for (int reg = 0; reg < 4; reg++) {
                int row = r0 + WR * 64 + mt * 16 + quad * 4 + reg;
                float v = acc[mt][nt][reg] + bv;
                if (row < N_NODES) {
                    Hout[(long)row * HID + col] = f2bf(v);
                    s += v;
                    q += v * v;
                }
            }
        }
        s += __shfl_xor(s, 16); s += __shfl_xor(s, 32);
        q += __shfl_xor(q, 16); q += __shfl_xor(q, 32);
        if (quad == 0) {
            float* base = &sred[(long)(blockIdx.x * 2 + WR) * 256];
            base[lcol]       = s;
            base[128 + lcol] = q;
        }
    }
}

// ---------------------------------------------------------------- BN reduce + prep
// sred: [RB128*2 blocks * 2 WR][256] rows; block b covers channels
// (b&1)*128..+127. Thread t<256 sums S for channel t, t>=256 sums Q.
__global__ __launch_bounds__(512) void bn_reduce_kernel(const float* __restrict__ sred,
                                                        const float* __restrict__ g,
                                                        const float* __restrict__ b,
                                                        float* __restrict__ ss) {
    __shared__ float qsm[256];
    int t   = threadIdx.x;
    int ch  = t & 255;
    int off = (t < 256) ? 0 : 128;
    int chh = ch >> 7;            // col_half owning this channel
    int lc  = ch & 127;
    float S0 = 0.f, S1 = 0.f, S2 = 0.f, S3 = 0.f;
    int rb = 0;
    for (; rb + 2 <= RB128; rb += 2) {
        long base0 = (long)(((rb + 0) * 2 + chh) * 2) * 256 + off + lc;
        long base1 = (long)(((rb + 1) * 2 + chh) * 2) * 256 + off + lc;
        S0 += sred[base0];        // WR 0
        S1 += sred[base0 + 256];  // WR 1
        S2 += sred[base1];
        S3 += sred[base1 + 256];
    }
    for (; rb < RB128; rb++) {
        long base0 = (long)((rb * 2 + chh) * 2) * 256 + off + lc;
        S0 += sred[base0];
        S1 += sred[base0 + 256];
    }
    float Sv = (S0 + S1) + (S2 + S3);
    if (t >= 256) qsm[ch] = Sv;
    __syncthreads();
    if (t < 256) {
        float mu  = Sv * (1.0f / N_NODES);
        float var = qsm[ch] * (1.0f / N_NODES) - mu * mu;
        var = fmaxf(var, 0.f);
        float sc = rsqrtf(var + BN_EPS) * g[ch];
        ss[ch]       = sc;
        ss[HID + ch] = b[ch] - mu * sc;
    }
}

// ---------------------------------------------------------------- BN + ELU
template<bool OUT32>
__global__ void bn_elu_kernel(const unsigned short* __restrict__ h, const float* __restrict__ ss,
                              void* __restrict__ out) {
    const int total4 = N_NODES * HID / 4;
    int i = blockIdx.x * blockDim.x + threadIdx.x;
    if (i >= total4) return;
    int c4 = (i % (HID / 4)) * 4;
    uint2 v = *(const uint2*)&h[(long)i * 4];
    float4 sc = *(const float4*)&ss[c4];
    float4 sh = *(const float4*)&ss[HID + c4];
    float in[4] = {bf2f((unsigned short)(v.x & 0xFFFF)), bf2f((unsigned short)(v.x >> 16)),
                   bf2f((unsigned short)(v.y & 0xFFFF)), bf2f((unsigned short)(v.y >> 16))};
    float scv[4] = {sc.x, sc.y, sc.z, sc.w};
    float shv[4] = {sh.x, sh.y, sh.z, sh.w};
    float o[4];
#pragma unroll
    for (int j = 0; j < 4; j++) {
        float t = fmaf(in[j], scv[j], shv[j]);
        o[j] = t > 0.f ? t : expm1f(t);
    }
    if (OUT32) {
        float4 ov = {o[0], o[1], o[2], o[3]};
        *(float4*)&((float*)out)[(long)i * 4] = ov;
    } else {
        unsigned short ov[4] = {f2bf(o[0]), f2bf(o[1]), f2bf(o[2]), f2bf(o[3])};
        *(uint2*)&((unsigned short*)out)[(long)i * 4] = *(const uint2*)ov;
    }
}

// ---------------------------------------------------------------- launch
extern "C" void kernel_launch(void* const* d_in, const int* in_sizes, int n_in,
                              void* d_out, int out_size, void* d_ws, size_t ws_size,
                              hipStream_t stream) {
    const float* x   = (const float*)d_in[0];
    const int*   ei  = (const int*)d_in[1];
    const int*   src = ei;
    const int*   dst = ei + N_EDGES;
    const float* Wn[3] = {(const float*)d_in[2],  (const float*)d_in[7],  (const float*)d_in[12]};
    const float* bn[3] = {(const float*)d_in[3],  (const float*)d_in[8],  (const float*)d_in[13]};
    const float* Wr[3] = {(const float*)d_in[4],  (const float*)d_in[9],  (const float*)d_in[14]};
    const float* g [3] = {(const float*)d_in[5],  (const float*)d_in[10], (const float*)d_in[15]};
    const float* b [3] = {(const float*)d_in[6],  (const float*)d_in[11], (const float*)d_in[16]};
    float* out = (float*)d_out;

    const size_t BF = (size_t)N_NODES * HID * 2;   // 25.6 MB (bf16 N x 256)
    char* ws = (char*)d_ws;
    unsigned short* B0  = (unsigned short*)(ws);                  // agg bf16
    unsigned short* B1  = (unsigned short*)(ws + BF);             // gemm out bf16
    unsigned short* B2  = (unsigned short*)(ws + 2 * BF);         // activations bf16
    unsigned short* XB  = (unsigned short*)(ws + 3 * BF);         // x bf16 [N,128] 12.8 MB
    char* ws2 = ws + 3 * BF + (size_t)N_NODES * F_IN * 2;
    unsigned short* WT0 = (unsigned short*)(ws2);                 // [256][256]
    unsigned short* WT1 = (unsigned short*)(ws2 + 256 * 256 * 2); // [256][512]
    unsigned short* WT2 = (unsigned short*)(ws2 + 256 * 256 * 2 + 256 * 512 * 2);
    char* ws3 = ws2 + 256 * 256 * 2 + 2 * (256 * 512 * 2);
    int*   row_ptr = (int*)ws3;
    int*   deg_i   = row_ptr + (N_NODES + 1);
    int*   partial = deg_i + N_NODES;
    int*   rank    = partial + SCAN_BLOCKS;
    int*   csr_src = rank + N_EDGES;
    float* sred    = (float*)(csr_src + N_EDGES);        // [RB128*2*2][256] partials
    float* ss      = sred + (size_t)RB128 * 2 * 2 * 256; // 2*HID scale/shift

    const int eb = (N_EDGES + 255) / 256;
    const int gather_blocks = (N_NODES + 3) / 4;
    const int elu_blocks = (N_NODES * HID / 4 + 255) / 256;
    const int prep_blocks = CAST_BLOCKS + SCAN_BLOCKS + WT_BLOCKS;
    const int gemm_blocks = RB128 * 2;   // 782

    // ---------------- one-time per call: prep + CSR (5 dispatches, no memset)
    prep_kernel<<<prep_blocks, 256, 0, stream>>>(x, XB,
        Wn[0], Wr[0], WT0, Wn[1], Wr[1], WT1, Wn[2], Wr[2], WT2, deg_i);
    hist_kernel<<<eb, 256, 0, stream>>>(dst, deg_i, rank);
    scan1_kernel<<<SCAN_BLOCKS, 256, 0, stream>>>(deg_i, row_ptr, partial);
    scan3_kernel<<<SCAN_BLOCKS, 256, 0, stream>>>(row_ptr, partial);
    fill_kernel<<<eb, 256, 0, stream>>>(src, dst, rank, row_ptr, csr_src);

    // ---------------- layer 0: XB[N,128] -> act B2
    gather_mean_kernel<F_IN><<<gather_blocks, 256, 0, stream>>>(XB, row_ptr, csr_src, B0);
    mfma_gemm_kernel<F_IN, F_IN><<<gemm_blocks, 256, 0, stream>>>(B0, XB, WT0, bn[0], B1, sred);
    bn_reduce_kernel<<<1, 512, 0, stream>>>(sred, g[0], b[0], ss);
    bn_elu_kernel<false><<<elu_blocks, 256, 0, stream>>>(B1, ss, B2);

    // ---------------- layer 1: B2 -> act B2
    gather_mean_kernel<HID><<<gather_blocks, 256, 0, stream>>>(B2, row_ptr, csr_src, B0);
    mfma_gemm_kernel<HID, HID><<<gemm_blocks, 256, 0, stream>>>(B0, B2, WT1, bn[1], B1, sred);
    bn_reduce_kernel<<<1, 512, 0, stream>>>(sred, g[1], b[1], ss);
    bn_elu_kernel<false><<<elu_blocks, 256, 0, stream>>>(B1, ss, B2);

    // ---------------- layer 2: B2 -> out (fp32)
    gather_mean_kernel<HID><<<gather_blocks, 256, 0, stream>>>(B2, row_ptr, csr_src, B0);
    mfma_gemm_kernel<HID, HID><<<gemm_blocks, 256, 0, stream>>>(B0, B2, WT2, bn[2], B1, sred);
    bn_reduce_kernel<<<1, 512, 0, stream>>>(sred, g[2], b[2], ss);
    bn_elu_kernel<true><<<elu_blocks, 256, 0, stream>>>(B1, ss, out);
}